// Round 6
// baseline (18115.100 us; speedup 1.0000x reference)
//
#include <hip/hip_runtime.h>

#define NROWS 131072
#define KE 2048

typedef unsigned long long u64_t;

__device__ __forceinline__ unsigned f32_key(float f) {
  unsigned u = __float_as_uint(f);
  return (u & 0x80000000u) ? ~u : (u | 0x80000000u);
}

// ---------------------------------------------------------------------------
// 64x64 tile f32 GEMM (UNCHANGED — enc1/dec2). MODE 0 only.
// ---------------------------------------------------------------------------
template <int MODE>
__global__ __launch_bounds__(256) void gemm64(
    const float* __restrict__ A, const float* __restrict__ B,
    const float* __restrict__ bias, float* __restrict__ C,
    int M, int N, int K,
    const int* __restrict__ gidx) {
  __shared__ __align__(16) float As[16][68];
  __shared__ __align__(16) float Bs[16][68];

  const int tid = threadIdx.x;
  const int tx = tid & 15;
  const int ty = tid >> 4;
  const int arow = blockIdx.x * 64;
  const int bcol = blockIdx.y * 64;

  const int lr = tid >> 2;
  const int lc = (tid & 3) * 4;
  int ga = arow + lr;
  if (MODE == 1) ga = gidx[ga];
  const float* Ap = A + (size_t)ga * K + lc;

  const int bkr = tid >> 4;
  const int bc4 = (tid & 15) * 4;
  const float* Bp = B + (size_t)bkr * N + bcol + bc4;

  float acc[4][4] = {};

  for (int kt = 0; kt < K; kt += 16) {
    float4 av = *reinterpret_cast<const float4*>(Ap);
    As[lc + 0][lr] = av.x;
    As[lc + 1][lr] = av.y;
    As[lc + 2][lr] = av.z;
    As[lc + 3][lr] = av.w;
    float4 bv = *reinterpret_cast<const float4*>(Bp);
    *reinterpret_cast<float4*>(&Bs[bkr][bc4]) = bv;
    Bp += (size_t)16 * N;
    Ap += 16;
    __syncthreads();
#pragma unroll
    for (int k = 0; k < 16; ++k) {
      float4 a = *reinterpret_cast<const float4*>(&As[k][ty * 4]);
      float4 b = *reinterpret_cast<const float4*>(&Bs[k][tx * 4]);
      acc[0][0] += a.x * b.x; acc[0][1] += a.x * b.y; acc[0][2] += a.x * b.z; acc[0][3] += a.x * b.w;
      acc[1][0] += a.y * b.x; acc[1][1] += a.y * b.y; acc[1][2] += a.y * b.z; acc[1][3] += a.y * b.w;
      acc[2][0] += a.z * b.x; acc[2][1] += a.z * b.y; acc[2][2] += a.z * b.z; acc[2][3] += a.z * b.w;
      acc[3][0] += a.w * b.x; acc[3][1] += a.w * b.y; acc[3][2] += a.w * b.z; acc[3][3] += a.w * b.w;
    }
    __syncthreads();
  }

#pragma unroll
  for (int i = 0; i < 4; ++i) {
    const int row = arow + ty * 4 + i;
    float4 v;
    v.x = fmaxf(acc[i][0] + bias[bcol + tx * 4 + 0], 0.f);
    v.y = fmaxf(acc[i][1] + bias[bcol + tx * 4 + 1], 0.f);
    v.z = fmaxf(acc[i][2] + bias[bcol + tx * 4 + 2], 0.f);
    v.w = fmaxf(acc[i][3] + bias[bcol + tx * 4 + 3], 0.f);
    *reinterpret_cast<float4*>(&C[(size_t)row * N + bcol + tx * 4]) = v;
  }
}

// ---------------------------------------------------------------------------
// 128x128 tile f32 GEMM (UNCHANGED — enc2/enc3/dec1/dec3). Modes 0/1/2.
// ---------------------------------------------------------------------------
template <int MODE>
__global__ __launch_bounds__(256) void gemm128(
    const float* __restrict__ A, const float* __restrict__ B,
    const float* __restrict__ bias, float* __restrict__ C,
    int N, int K,
    const int* __restrict__ gidx,
    const float* __restrict__ X,
    float* __restrict__ parts) {
  __shared__ __align__(16) char smem[17408];
  float (*As)[132] = (float(*)[132])smem;
  float (*Bs)[132] = (float(*)[132])(smem + 8448);

  const int tid = threadIdx.x;
  const int tx = tid & 15;
  const int ty = tid >> 4;
  const int arow = blockIdx.x * 128;
  const int bcol = blockIdx.y * 128;

  const int r0 = tid >> 2;
  const int r1 = r0 + 64;
  const int lc = (tid & 3) * 4;
  int ga0 = arow + r0, ga1 = arow + r1;
  if (MODE == 1) { ga0 = gidx[ga0]; ga1 = gidx[ga1]; }
  const float* Ap0 = A + (size_t)ga0 * K + lc;
  const float* Ap1 = A + (size_t)ga1 * K + lc;

  const int bk0 = tid >> 5;
  const int bc0 = (tid & 31) * 4;
  const float* Bp0 = B + (size_t)bk0 * N + bcol + bc0;
  const float* Bp1 = B + (size_t)(bk0 + 8) * N + bcol + bc0;

  float acc[8][8] = {};

  for (int kt = 0; kt < K; kt += 16) {
    float4 a0 = *reinterpret_cast<const float4*>(Ap0);
    float4 a1 = *reinterpret_cast<const float4*>(Ap1);
    As[lc + 0][r0] = a0.x; As[lc + 1][r0] = a0.y; As[lc + 2][r0] = a0.z; As[lc + 3][r0] = a0.w;
    As[lc + 0][r1] = a1.x; As[lc + 1][r1] = a1.y; As[lc + 2][r1] = a1.z; As[lc + 3][r1] = a1.w;
    float4 b0 = *reinterpret_cast<const float4*>(Bp0);
    float4 b1 = *reinterpret_cast<const float4*>(Bp1);
    *reinterpret_cast<float4*>(&Bs[bk0][bc0]) = b0;
    *reinterpret_cast<float4*>(&Bs[bk0 + 8][bc0]) = b1;
    Bp0 += (size_t)16 * N; Bp1 += (size_t)16 * N;
    Ap0 += 16; Ap1 += 16;
    __syncthreads();
#pragma unroll
    for (int k = 0; k < 16; ++k) {
      float4 av0 = *reinterpret_cast<const float4*>(&As[k][ty * 4]);
      float4 av1 = *reinterpret_cast<const float4*>(&As[k][64 + ty * 4]);
      float4 bv0 = *reinterpret_cast<const float4*>(&Bs[k][tx * 4]);
      float4 bv1 = *reinterpret_cast<const float4*>(&Bs[k][64 + tx * 4]);
      const float a[8] = {av0.x, av0.y, av0.z, av0.w, av1.x, av1.y, av1.z, av1.w};
      const float b[8] = {bv0.x, bv0.y, bv0.z, bv0.w, bv1.x, bv1.y, bv1.z, bv1.w};
#pragma unroll
      for (int i = 0; i < 8; ++i)
#pragma unroll
        for (int j = 0; j < 8; ++j) acc[i][j] += a[i] * b[j];
    }
    __syncthreads();
  }

  if (MODE == 0 || MODE == 1) {
#pragma unroll
    for (int i = 0; i < 8; ++i) {
      const int row = arow + (i >> 2) * 64 + ty * 4 + (i & 3);
      const int c0 = bcol + tx * 4;
      const int c1 = bcol + 64 + tx * 4;
      float4 v0, v1;
      v0.x = fmaxf(acc[i][0] + bias[c0 + 0], 0.f);
      v0.y = fmaxf(acc[i][1] + bias[c0 + 1], 0.f);
      v0.z = fmaxf(acc[i][2] + bias[c0 + 2], 0.f);
      v0.w = fmaxf(acc[i][3] + bias[c0 + 3], 0.f);
      v1.x = fmaxf(acc[i][4] + bias[c1 + 0], 0.f);
      v1.y = fmaxf(acc[i][5] + bias[c1 + 1], 0.f);
      v1.z = fmaxf(acc[i][6] + bias[c1 + 2], 0.f);
      v1.w = fmaxf(acc[i][7] + bias[c1 + 3], 0.f);
      *reinterpret_cast<float4*>(&C[(size_t)row * N + c0]) = v0;
      *reinterpret_cast<float4*>(&C[(size_t)row * N + c1]) = v1;
    }
  } else if (MODE == 2) {
    float local = 0.f;
#pragma unroll
    for (int i = 0; i < 8; ++i) {
      const int row = arow + (i >> 2) * 64 + ty * 4 + (i & 3);
#pragma unroll
      for (int j = 0; j < 8; ++j) {
        const int col = bcol + (j >> 2) * 64 + tx * 4 + (j & 3);
        float v = fmaxf(acc[i][j] + bias[col], 0.f);
        float d = v - X[(size_t)row * N + col];
        local += d * d;
      }
    }
    float* rbuf = (float*)smem;
    rbuf[tid] = local;
    __syncthreads();
    for (int off = 128; off > 0; off >>= 1) {
      if (tid < off) rbuf[tid] += rbuf[tid + off];
      __syncthreads();
    }
    if (tid == 0) parts[blockIdx.y * gridDim.x + blockIdx.x] = rbuf[0];
  }
}

// ---------------------------------------------------------------------------
// dist16x8: distance + argmin. Tile 256 rows x 128 cols, 256 threads,
// per-thread 16 rows x 8 cols (128 acc) in 4x2 quadrants of 4.
// DS-pipe math: per wave per k = 4 broadcast A-reads + 2 B-reads (~56 cyc)
// vs 256 VALU cyc/SIMD -> VALU-bound. Double-buffered LDS, global loads
// issued at iter top (hidden under 4096-cyc FMA phase), reg->LDS writes
// after compute, ONE barrier per tile. 2 waves/SIMD is enough because no
// latency is exposed on the critical path.
// XCD swizzle: all 16 col-tiles of a row-panel land on one XCD (d%8).
// k accumulation strictly ascending (t outer, k inner) -> bit-identical
// scores -> argmin identical to reference.
// ---------------------------------------------------------------------------
__global__ __launch_bounds__(256, 2) void dist16x8(
    const float* __restrict__ A,   // z_e [NROWS][256]
    const float* __restrict__ B,   // emb [KE][256]
    const float* __restrict__ zsq,
    const float* __restrict__ esq,
    u64_t* __restrict__ keys) {
  // per buffer: As 16x260 f32 (16640 B) + Bs 16x132 f32 (8448 B) = 25088 B
  __shared__ __align__(16) char smem[50176];

  const int tid = threadIdx.x;
  const int tx = tid & 15;
  const int ty = tid >> 4;

  // XCD-aware block swizzle: 8192 blocks; dispatch round-robins d%8 over XCDs.
  const int d = blockIdx.x;
  const int xcd = d & 7;
  const int slot = d >> 3;
  const int row_tile = xcd + 8 * (slot >> 4);  // 0..511
  const int col_tile = slot & 15;              // 0..15
  const int arow = row_tile * 256;
  const int bcol = col_tile * 128;

  // staging mapping: 4 lanes per row, 16B each (coalesced 64B per row-segment)
  const int r0 = tid >> 2;        // 0..63
  const int lc = (tid & 3) * 4;   // 0,4,8,12
  const float* ApG = A + (size_t)(arow + r0) * 256 + lc;
  const float* BpG = B + (size_t)(bcol + r0) * 256 + lc;

  float4 sa0, sa1, sa2, sa3, sb0, sb1;

#define DLOAD(kt)                                              \
  do {                                                         \
    sa0 = *reinterpret_cast<const float4*>(ApG + (kt));        \
    sa1 = *reinterpret_cast<const float4*>(ApG + 16384 + (kt));\
    sa2 = *reinterpret_cast<const float4*>(ApG + 32768 + (kt));\
    sa3 = *reinterpret_cast<const float4*>(ApG + 49152 + (kt));\
    sb0 = *reinterpret_cast<const float4*>(BpG + (kt));        \
    sb1 = *reinterpret_cast<const float4*>(BpG + 16384 + (kt));\
  } while (0)

#define DWRITE(buf)                                            \
  do {                                                         \
    float* As = (float*)(buf);                                 \
    float* Bs = (float*)((buf) + 16640);                       \
    As[(lc + 0) * 260 + r0] = sa0.x; As[(lc + 1) * 260 + r0] = sa0.y; \
    As[(lc + 2) * 260 + r0] = sa0.z; As[(lc + 3) * 260 + r0] = sa0.w; \
    As[(lc + 0) * 260 + r0 + 64] = sa1.x; As[(lc + 1) * 260 + r0 + 64] = sa1.y; \
    As[(lc + 2) * 260 + r0 + 64] = sa1.z; As[(lc + 3) * 260 + r0 + 64] = sa1.w; \
    As[(lc + 0) * 260 + r0 + 128] = sa2.x; As[(lc + 1) * 260 + r0 + 128] = sa2.y; \
    As[(lc + 2) * 260 + r0 + 128] = sa2.z; As[(lc + 3) * 260 + r0 + 128] = sa2.w; \
    As[(lc + 0) * 260 + r0 + 192] = sa3.x; As[(lc + 1) * 260 + r0 + 192] = sa3.y; \
    As[(lc + 2) * 260 + r0 + 192] = sa3.z; As[(lc + 3) * 260 + r0 + 192] = sa3.w; \
    Bs[(lc + 0) * 132 + r0] = sb0.x; Bs[(lc + 1) * 132 + r0] = sb0.y; \
    Bs[(lc + 2) * 132 + r0] = sb0.z; Bs[(lc + 3) * 132 + r0] = sb0.w; \
    Bs[(lc + 0) * 132 + r0 + 64] = sb1.x; Bs[(lc + 1) * 132 + r0 + 64] = sb1.y; \
    Bs[(lc + 2) * 132 + r0 + 64] = sb1.z; Bs[(lc + 3) * 132 + r0 + 64] = sb1.w; \
  } while (0)

  float acc[16][8] = {};

  // prologue: stage tile 0 into buffer 0
  DLOAD(0);
  DWRITE(smem);

  for (int t = 0; t < 16; ++t) {
    if (t < 15) DLOAD((t + 1) * 16);   // VMEM in flight under compute
    __syncthreads();                    // buf[t&1] writes visible; buf[(t+1)&1] reads done
    {
      const char* buf = smem + (size_t)(t & 1) * 25088;
      const float* As = (const float*)buf;
      const float* Bs = (const float*)(buf + 16640);
#pragma unroll
      for (int k = 0; k < 16; ++k) {
        float4 a0 = *reinterpret_cast<const float4*>(As + k * 260 + ty * 4);
        float4 a1 = *reinterpret_cast<const float4*>(As + k * 260 + 64 + ty * 4);
        float4 a2 = *reinterpret_cast<const float4*>(As + k * 260 + 128 + ty * 4);
        float4 a3 = *reinterpret_cast<const float4*>(As + k * 260 + 192 + ty * 4);
        float4 b0 = *reinterpret_cast<const float4*>(Bs + k * 132 + tx * 4);
        float4 b1 = *reinterpret_cast<const float4*>(Bs + k * 132 + 64 + tx * 4);
        const float a[16] = {a0.x, a0.y, a0.z, a0.w, a1.x, a1.y, a1.z, a1.w,
                             a2.x, a2.y, a2.z, a2.w, a3.x, a3.y, a3.z, a3.w};
        const float b[8] = {b0.x, b0.y, b0.z, b0.w, b1.x, b1.y, b1.z, b1.w};
#pragma unroll
        for (int i = 0; i < 16; ++i)
#pragma unroll
          for (int j = 0; j < 8; ++j) acc[i][j] += a[i] * b[j];
      }
    }
    if (t < 15) DWRITE(smem + (size_t)((t + 1) & 1) * 25088);
  }
  __syncthreads();  // before smem reuse as mb

#undef DLOAD
#undef DWRITE

  // epilogue: scores + per-block argmin (exact reference rounding)
  u64_t (*mb)[17] = (u64_t(*)[17])smem;  // 256 x 17 x 8 = 34816 B
#pragma unroll
  for (int i = 0; i < 16; ++i) {
    const int row = (i >> 2) * 64 + ty * 4 + (i & 3);
    const float zs = zsq[arow + row];
    u64_t best = ~0ull;
#pragma unroll
    for (int j = 0; j < 8; ++j) {
      const int col = bcol + (j >> 2) * 64 + tx * 4 + (j & 3);
      // exact reference rounding: (z_sq - 2*p) + e_sq  (2*p exact in fp)
      float dsc = (zs - 2.0f * acc[i][j]) + esq[col];
      u64_t kk = ((u64_t)f32_key(dsc) << 32) | (unsigned)col;
      if (kk < best) best = kk;
    }
    mb[row][tx] = best;
  }
  __syncthreads();
  {
    u64_t b = mb[tid][0];
#pragma unroll
    for (int t2 = 1; t2 < 16; ++t2) {
      u64_t v = mb[tid][t2];
      if (v < b) b = v;
    }
    atomicMin(&keys[arow + tid], b);
  }
}

// sum of squares per row (256 cols); block = 4 rows x 64 lanes
__global__ __launch_bounds__(256) void rowsq(const float* __restrict__ src,
                                             float* __restrict__ dst, int rows) {
  const int sub = threadIdx.x >> 6;
  const int lane = threadIdx.x & 63;
  const int r = blockIdx.x * 4 + sub;
  if (r >= rows) return;
  const float* p = src + (size_t)r * 256;
  float s = 0.f;
#pragma unroll
  for (int j = 0; j < 4; ++j) {
    float v = p[lane + 64 * j];
    s += v * v;
  }
#pragma unroll
  for (int off = 32; off > 0; off >>= 1) s += __shfl_down(s, off, 64);
  if (lane == 0) dst[r] = s;
}

__global__ __launch_bounds__(256) void init_keys(u64_t* __restrict__ keys) {
  keys[(size_t)blockIdx.x * 256 + threadIdx.x] = ~0ull;
}

// per row: idx from key, write z_latent = z + (e - z), quant-loss partial sums
__global__ __launch_bounds__(256) void gather_quant(
    const u64_t* __restrict__ keys, const float* __restrict__ emb,
    const float* __restrict__ z_e, float* __restrict__ zlat,
    int* __restrict__ idx_out, float* __restrict__ qparts) {
  const int sub = threadIdx.x >> 6;
  const int lane = threadIdx.x & 63;
  const int r = blockIdx.x * 4 + sub;
  const int idx = (int)(keys[r] & 0xFFFFFFFFull);
  if (lane == 0) idx_out[r] = idx;
  float s = 0.f;
#pragma unroll
  for (int j = 0; j < 4; ++j) {
    const int d = lane + 64 * j;
    float e = emb[(size_t)idx * 256 + d];
    float z = z_e[(size_t)r * 256 + d];
    float df = e - z;
    s += df * df;
    zlat[(size_t)r * 256 + d] = z + df;  // fl(z_e + fl(z_q - z_e)) — exact ref order
  }
#pragma unroll
  for (int off = 32; off > 0; off >>= 1) s += __shfl_down(s, off, 64);
  __shared__ float red[4];
  if (lane == 0) red[sub] = s;
  __syncthreads();
  if (threadIdx.x == 0) qparts[blockIdx.x] = (red[0] + red[1]) + (red[2] + red[3]);
}

__global__ __launch_bounds__(256) void final_loss(
    const float* __restrict__ qparts, int nq,
    const float* __restrict__ rparts, int nr, float* __restrict__ out) {
  const int tid = threadIdx.x;
  double sq = 0.0, sr = 0.0;
  for (int i = tid; i < nq; i += 256) sq += (double)qparts[i];
  for (int i = tid; i < nr; i += 256) sr += (double)rparts[i];
  __shared__ double bq[256], br[256];
  bq[tid] = sq;
  br[tid] = sr;
  __syncthreads();
  for (int off = 128; off > 0; off >>= 1) {
    if (tid < off) {
      bq[tid] += bq[tid + off];
      br[tid] += br[tid + off];
    }
    __syncthreads();
  }
  if (tid == 0) {
    double qm = bq[0] / ((double)NROWS * 256.0);
    double rm = br[0] / ((double)NROWS * 512.0);
    out[(size_t)NROWS * 256] = (float)(rm + 1.25 * qm);  // recon + (1+BETA)*quant
  }
}

extern "C" void kernel_launch(void* const* d_in, const int* in_sizes, int n_in,
                              void* d_out, int out_size, void* d_ws, size_t ws_size,
                              hipStream_t stream) {
  const float* x   = (const float*)d_in[0];
  const float* ew1 = (const float*)d_in[1];
  const float* eb1 = (const float*)d_in[2];
  const float* ew2 = (const float*)d_in[3];
  const float* eb2 = (const float*)d_in[4];
  const float* ew3 = (const float*)d_in[5];
  const float* eb3 = (const float*)d_in[6];
  const float* dw1 = (const float*)d_in[7];
  const float* db1 = (const float*)d_in[8];
  const float* dw2 = (const float*)d_in[9];
  const float* db2 = (const float*)d_in[10];
  const float* dw3 = (const float*)d_in[11];
  const float* db3 = (const float*)d_in[12];
  const float* emb = (const float*)d_in[13];

  char* ws = (char*)d_ws;
  float* h1     = (float*)(ws);                    // N x 64   (reused as dec h2)
  float* h2     = (float*)(ws + 33554432ull);      // N x 128  (reused as dec h1)
  float* z_e    = (float*)(ws + 100663296ull);     // N x 256
  float* zsq    = (float*)(ws + 234881024ull);     // N
  float* esq    = (float*)(ws + 235405312ull);     // KE
  u64_t* keys   = (u64_t*)(ws + 235413504ull);     // N
  int* idx      = (int*)(ws + 236462080ull);       // N
  float* qparts = (float*)(ws + 236986368ull);     // N/4 = 32768
  float* rparts = (float*)(ws + 237117440ull);     // 1024*4 = 4096

  float* out = (float*)d_out;

  dim3 blk(256);

  // encoder: 512 -> 64 -> 128 -> 256  (all unchanged -> bit-exact z_e)
  gemm64<0><<<dim3(NROWS / 64, 1), blk, 0, stream>>>(x, ew1, eb1, h1, NROWS, 64, 512,
      nullptr);
  gemm128<0><<<dim3(NROWS / 128, 1), blk, 0, stream>>>(h1, ew2, eb2, h2,
      128, 64, nullptr, nullptr, nullptr);
  gemm128<0><<<dim3(NROWS / 128, 2), blk, 0, stream>>>(h2, ew3, eb3, z_e,
      256, 128, nullptr, nullptr, nullptr);

  rowsq<<<dim3(NROWS / 4), blk, 0, stream>>>(z_e, zsq, NROWS);
  rowsq<<<dim3(KE / 4), blk, 0, stream>>>(emb, esq, KE);
  init_keys<<<dim3(NROWS / 256), blk, 0, stream>>>(keys);

  // distances + argmin: 256x128 blocks, 16x8/thread, XCD-swizzled grid
  dist16x8<<<dim3((NROWS / 256) * (KE / 128)), blk, 0, stream>>>(z_e, emb, zsq, esq, keys);

  gather_quant<<<dim3(NROWS / 4), blk, 0, stream>>>(keys, emb, z_e, out, idx, qparts);

  // decoder: 256 -> 128 -> 64 -> 512 (loss-only path, 2% threshold)
  gemm128<1><<<dim3(NROWS / 128, 1), blk, 0, stream>>>(emb, dw1, db1, h2,
      128, 256, idx, nullptr, nullptr);
  gemm64<0><<<dim3(NROWS / 64, 1), blk, 0, stream>>>(h2, dw2, db2, h1, NROWS, 64, 128,
      nullptr);
  gemm128<2><<<dim3(NROWS / 128, 4), blk, 0, stream>>>(h1, dw3, db3, nullptr,
      512, 64, nullptr, x, rparts);

  final_loss<<<dim3(1), blk, 0, stream>>>(qparts, NROWS / 4, rparts, 4096, out);
}

// Round 7
// 4743.336 us; speedup vs baseline: 3.8191x; 3.8191x over previous
//
#include <hip/hip_runtime.h>

#define NROWS 131072
#define KE 2048

typedef unsigned long long u64_t;

__device__ __forceinline__ unsigned f32_key(float f) {
  unsigned u = __float_as_uint(f);
  return (u & 0x80000000u) ? ~u : (u | 0x80000000u);
}

// ---------------------------------------------------------------------------
// 64x64 tile f32 GEMM (UNCHANGED — enc1/dec2). MODE 0 only.
// ---------------------------------------------------------------------------
template <int MODE>
__global__ __launch_bounds__(256) void gemm64(
    const float* __restrict__ A, const float* __restrict__ B,
    const float* __restrict__ bias, float* __restrict__ C,
    int M, int N, int K,
    const int* __restrict__ gidx) {
  __shared__ __align__(16) float As[16][68];
  __shared__ __align__(16) float Bs[16][68];

  const int tid = threadIdx.x;
  const int tx = tid & 15;
  const int ty = tid >> 4;
  const int arow = blockIdx.x * 64;
  const int bcol = blockIdx.y * 64;

  const int lr = tid >> 2;
  const int lc = (tid & 3) * 4;
  int ga = arow + lr;
  if (MODE == 1) ga = gidx[ga];
  const float* Ap = A + (size_t)ga * K + lc;

  const int bkr = tid >> 4;
  const int bc4 = (tid & 15) * 4;
  const float* Bp = B + (size_t)bkr * N + bcol + bc4;

  float acc[4][4] = {};

  for (int kt = 0; kt < K; kt += 16) {
    float4 av = *reinterpret_cast<const float4*>(Ap);
    As[lc + 0][lr] = av.x;
    As[lc + 1][lr] = av.y;
    As[lc + 2][lr] = av.z;
    As[lc + 3][lr] = av.w;
    float4 bv = *reinterpret_cast<const float4*>(Bp);
    *reinterpret_cast<float4*>(&Bs[bkr][bc4]) = bv;
    Bp += (size_t)16 * N;
    Ap += 16;
    __syncthreads();
#pragma unroll
    for (int k = 0; k < 16; ++k) {
      float4 a = *reinterpret_cast<const float4*>(&As[k][ty * 4]);
      float4 b = *reinterpret_cast<const float4*>(&Bs[k][tx * 4]);
      acc[0][0] += a.x * b.x; acc[0][1] += a.x * b.y; acc[0][2] += a.x * b.z; acc[0][3] += a.x * b.w;
      acc[1][0] += a.y * b.x; acc[1][1] += a.y * b.y; acc[1][2] += a.y * b.z; acc[1][3] += a.y * b.w;
      acc[2][0] += a.z * b.x; acc[2][1] += a.z * b.y; acc[2][2] += a.z * b.z; acc[2][3] += a.z * b.w;
      acc[3][0] += a.w * b.x; acc[3][1] += a.w * b.y; acc[3][2] += a.w * b.z; acc[3][3] += a.w * b.w;
    }
    __syncthreads();
  }

#pragma unroll
  for (int i = 0; i < 4; ++i) {
    const int row = arow + ty * 4 + i;
    float4 v;
    v.x = fmaxf(acc[i][0] + bias[bcol + tx * 4 + 0], 0.f);
    v.y = fmaxf(acc[i][1] + bias[bcol + tx * 4 + 1], 0.f);
    v.z = fmaxf(acc[i][2] + bias[bcol + tx * 4 + 2], 0.f);
    v.w = fmaxf(acc[i][3] + bias[bcol + tx * 4 + 3], 0.f);
    *reinterpret_cast<float4*>(&C[(size_t)row * N + bcol + tx * 4]) = v;
  }
}

// ---------------------------------------------------------------------------
// 128x128 tile f32 GEMM (UNCHANGED — enc2/enc3/dec1/dec3). Modes 0/1/2.
// ---------------------------------------------------------------------------
template <int MODE>
__global__ __launch_bounds__(256) void gemm128(
    const float* __restrict__ A, const float* __restrict__ B,
    const float* __restrict__ bias, float* __restrict__ C,
    int N, int K,
    const int* __restrict__ gidx,
    const float* __restrict__ X,
    float* __restrict__ parts) {
  __shared__ __align__(16) char smem[17408];
  float (*As)[132] = (float(*)[132])smem;
  float (*Bs)[132] = (float(*)[132])(smem + 8448);

  const int tid = threadIdx.x;
  const int tx = tid & 15;
  const int ty = tid >> 4;
  const int arow = blockIdx.x * 128;
  const int bcol = blockIdx.y * 128;

  const int r0 = tid >> 2;
  const int r1 = r0 + 64;
  const int lc = (tid & 3) * 4;
  int ga0 = arow + r0, ga1 = arow + r1;
  if (MODE == 1) { ga0 = gidx[ga0]; ga1 = gidx[ga1]; }
  const float* Ap0 = A + (size_t)ga0 * K + lc;
  const float* Ap1 = A + (size_t)ga1 * K + lc;

  const int bk0 = tid >> 5;
  const int bc0 = (tid & 31) * 4;
  const float* Bp0 = B + (size_t)bk0 * N + bcol + bc0;
  const float* Bp1 = B + (size_t)(bk0 + 8) * N + bcol + bc0;

  float acc[8][8] = {};

  for (int kt = 0; kt < K; kt += 16) {
    float4 a0 = *reinterpret_cast<const float4*>(Ap0);
    float4 a1 = *reinterpret_cast<const float4*>(Ap1);
    As[lc + 0][r0] = a0.x; As[lc + 1][r0] = a0.y; As[lc + 2][r0] = a0.z; As[lc + 3][r0] = a0.w;
    As[lc + 0][r1] = a1.x; As[lc + 1][r1] = a1.y; As[lc + 2][r1] = a1.z; As[lc + 3][r1] = a1.w;
    float4 b0 = *reinterpret_cast<const float4*>(Bp0);
    float4 b1 = *reinterpret_cast<const float4*>(Bp1);
    *reinterpret_cast<float4*>(&Bs[bk0][bc0]) = b0;
    *reinterpret_cast<float4*>(&Bs[bk0 + 8][bc0]) = b1;
    Bp0 += (size_t)16 * N; Bp1 += (size_t)16 * N;
    Ap0 += 16; Ap1 += 16;
    __syncthreads();
#pragma unroll
    for (int k = 0; k < 16; ++k) {
      float4 av0 = *reinterpret_cast<const float4*>(&As[k][ty * 4]);
      float4 av1 = *reinterpret_cast<const float4*>(&As[k][64 + ty * 4]);
      float4 bv0 = *reinterpret_cast<const float4*>(&Bs[k][tx * 4]);
      float4 bv1 = *reinterpret_cast<const float4*>(&Bs[k][64 + tx * 4]);
      const float a[8] = {av0.x, av0.y, av0.z, av0.w, av1.x, av1.y, av1.z, av1.w};
      const float b[8] = {bv0.x, bv0.y, bv0.z, bv0.w, bv1.x, bv1.y, bv1.z, bv1.w};
#pragma unroll
      for (int i = 0; i < 8; ++i)
#pragma unroll
        for (int j = 0; j < 8; ++j) acc[i][j] += a[i] * b[j];
    }
    __syncthreads();
  }

  if (MODE == 0 || MODE == 1) {
#pragma unroll
    for (int i = 0; i < 8; ++i) {
      const int row = arow + (i >> 2) * 64 + ty * 4 + (i & 3);
      const int c0 = bcol + tx * 4;
      const int c1 = bcol + 64 + tx * 4;
      float4 v0, v1;
      v0.x = fmaxf(acc[i][0] + bias[c0 + 0], 0.f);
      v0.y = fmaxf(acc[i][1] + bias[c0 + 1], 0.f);
      v0.z = fmaxf(acc[i][2] + bias[c0 + 2], 0.f);
      v0.w = fmaxf(acc[i][3] + bias[c0 + 3], 0.f);
      v1.x = fmaxf(acc[i][4] + bias[c1 + 0], 0.f);
      v1.y = fmaxf(acc[i][5] + bias[c1 + 1], 0.f);
      v1.z = fmaxf(acc[i][6] + bias[c1 + 2], 0.f);
      v1.w = fmaxf(acc[i][7] + bias[c1 + 3], 0.f);
      *reinterpret_cast<float4*>(&C[(size_t)row * N + c0]) = v0;
      *reinterpret_cast<float4*>(&C[(size_t)row * N + c1]) = v1;
    }
  } else if (MODE == 2) {
    float local = 0.f;
#pragma unroll
    for (int i = 0; i < 8; ++i) {
      const int row = arow + (i >> 2) * 64 + ty * 4 + (i & 3);
#pragma unroll
      for (int j = 0; j < 8; ++j) {
        const int col = bcol + (j >> 2) * 64 + tx * 4 + (j & 3);
        float v = fmaxf(acc[i][j] + bias[col], 0.f);
        float d = v - X[(size_t)row * N + col];
        local += d * d;
      }
    }
    float* rbuf = (float*)smem;
    rbuf[tid] = local;
    __syncthreads();
    for (int off = 128; off > 0; off >>= 1) {
      if (tid < off) rbuf[tid] += rbuf[tid + off];
      __syncthreads();
    }
    if (tid == 0) parts[blockIdx.y * gridDim.x + blockIdx.x] = rbuf[0];
  }
}

// ---------------------------------------------------------------------------
// dist16x8: distance + argmin. Tile 256 rows x 128 cols, 256 threads,
// per-thread 16 rows x 8 cols (128 acc) in 4x2 quadrants of 4.
// Round-7 change: __launch_bounds__(256, 1) -> VGPR cap 512. Round 6's
// (256,2) made hipcc allocate only 128 VGPRs and spill the accumulator to
// scratch (53 GB WRITE_SIZE per dispatch). Live set ~190 regs fits easily
// under 512; expect ~200 VGPR, 2 waves/SIMD, zero scratch.
// Schedule: global loads at iter top (hidden under the ~4096-cyc FMA phase),
// reg->LDS writes after compute, ONE barrier per tile (T14 async split).
// k accumulation strictly ascending (t outer, k inner) -> bit-identical
// scores -> argmin identical to reference.
// ---------------------------------------------------------------------------
__global__ __launch_bounds__(256, 1) void dist16x8(
    const float* __restrict__ A,   // z_e [NROWS][256]
    const float* __restrict__ B,   // emb [KE][256]
    const float* __restrict__ zsq,
    const float* __restrict__ esq,
    u64_t* __restrict__ keys) {
  // per buffer: As 16x260 f32 (16640 B) + Bs 16x132 f32 (8448 B) = 25088 B
  __shared__ __align__(16) char smem[50176];

  const int tid = threadIdx.x;
  const int tx = tid & 15;
  const int ty = tid >> 4;

  // XCD-aware block swizzle: 8192 blocks; dispatch round-robins d%8 over XCDs.
  const int d = blockIdx.x;
  const int xcd = d & 7;
  const int slot = d >> 3;
  const int row_tile = xcd + 8 * (slot >> 4);  // 0..511
  const int col_tile = slot & 15;              // 0..15
  const int arow = row_tile * 256;
  const int bcol = col_tile * 128;

  // staging mapping: 4 lanes per row, 16B each (coalesced 64B per row-segment)
  const int r0 = tid >> 2;        // 0..63
  const int lc = (tid & 3) * 4;   // 0,4,8,12
  const float* ApG = A + (size_t)(arow + r0) * 256 + lc;
  const float* BpG = B + (size_t)(bcol + r0) * 256 + lc;

  float4 sa0, sa1, sa2, sa3, sb0, sb1;

#define DLOAD(kt)                                              \
  do {                                                         \
    sa0 = *reinterpret_cast<const float4*>(ApG + (kt));        \
    sa1 = *reinterpret_cast<const float4*>(ApG + 16384 + (kt));\
    sa2 = *reinterpret_cast<const float4*>(ApG + 32768 + (kt));\
    sa3 = *reinterpret_cast<const float4*>(ApG + 49152 + (kt));\
    sb0 = *reinterpret_cast<const float4*>(BpG + (kt));        \
    sb1 = *reinterpret_cast<const float4*>(BpG + 16384 + (kt));\
  } while (0)

#define DWRITE(buf)                                            \
  do {                                                         \
    float* As = (float*)(buf);                                 \
    float* Bs = (float*)((buf) + 16640);                       \
    As[(lc + 0) * 260 + r0] = sa0.x; As[(lc + 1) * 260 + r0] = sa0.y; \
    As[(lc + 2) * 260 + r0] = sa0.z; As[(lc + 3) * 260 + r0] = sa0.w; \
    As[(lc + 0) * 260 + r0 + 64] = sa1.x; As[(lc + 1) * 260 + r0 + 64] = sa1.y; \
    As[(lc + 2) * 260 + r0 + 64] = sa1.z; As[(lc + 3) * 260 + r0 + 64] = sa1.w; \
    As[(lc + 0) * 260 + r0 + 128] = sa2.x; As[(lc + 1) * 260 + r0 + 128] = sa2.y; \
    As[(lc + 2) * 260 + r0 + 128] = sa2.z; As[(lc + 3) * 260 + r0 + 128] = sa2.w; \
    As[(lc + 0) * 260 + r0 + 192] = sa3.x; As[(lc + 1) * 260 + r0 + 192] = sa3.y; \
    As[(lc + 2) * 260 + r0 + 192] = sa3.z; As[(lc + 3) * 260 + r0 + 192] = sa3.w; \
    Bs[(lc + 0) * 132 + r0] = sb0.x; Bs[(lc + 1) * 132 + r0] = sb0.y; \
    Bs[(lc + 2) * 132 + r0] = sb0.z; Bs[(lc + 3) * 132 + r0] = sb0.w; \
    Bs[(lc + 0) * 132 + r0 + 64] = sb1.x; Bs[(lc + 1) * 132 + r0 + 64] = sb1.y; \
    Bs[(lc + 2) * 132 + r0 + 64] = sb1.z; Bs[(lc + 3) * 132 + r0 + 64] = sb1.w; \
  } while (0)

  float acc[16][8] = {};

  // prologue: stage tile 0 into buffer 0
  DLOAD(0);
  DWRITE(smem);

  for (int t = 0; t < 16; ++t) {
    if (t < 15) DLOAD((t + 1) * 16);   // VMEM in flight under compute
    __syncthreads();                    // buf[t&1] writes visible; buf[(t+1)&1] reads done
    {
      const char* buf = smem + (size_t)(t & 1) * 25088;
      const float* As = (const float*)buf;
      const float* Bs = (const float*)(buf + 16640);
#pragma unroll
      for (int k = 0; k < 16; ++k) {
        float4 a0 = *reinterpret_cast<const float4*>(As + k * 260 + ty * 4);
        float4 a1 = *reinterpret_cast<const float4*>(As + k * 260 + 64 + ty * 4);
        float4 a2 = *reinterpret_cast<const float4*>(As + k * 260 + 128 + ty * 4);
        float4 a3 = *reinterpret_cast<const float4*>(As + k * 260 + 192 + ty * 4);
        float4 b0 = *reinterpret_cast<const float4*>(Bs + k * 132 + tx * 4);
        float4 b1 = *reinterpret_cast<const float4*>(Bs + k * 132 + 64 + tx * 4);
        const float a[16] = {a0.x, a0.y, a0.z, a0.w, a1.x, a1.y, a1.z, a1.w,
                             a2.x, a2.y, a2.z, a2.w, a3.x, a3.y, a3.z, a3.w};
        const float b[8] = {b0.x, b0.y, b0.z, b0.w, b1.x, b1.y, b1.z, b1.w};
#pragma unroll
        for (int i = 0; i < 16; ++i)
#pragma unroll
          for (int j = 0; j < 8; ++j) acc[i][j] += a[i] * b[j];
      }
    }
    if (t < 15) DWRITE(smem + (size_t)((t + 1) & 1) * 25088);
  }
  __syncthreads();  // before smem reuse as mb

#undef DLOAD
#undef DWRITE

  // epilogue: scores + per-block argmin (exact reference rounding)
  u64_t (*mb)[17] = (u64_t(*)[17])smem;  // 256 x 17 x 8 = 34816 B
#pragma unroll
  for (int i = 0; i < 16; ++i) {
    const int row = (i >> 2) * 64 + ty * 4 + (i & 3);
    const float zs = zsq[arow + row];
    u64_t best = ~0ull;
#pragma unroll
    for (int j = 0; j < 8; ++j) {
      const int col = bcol + (j >> 2) * 64 + tx * 4 + (j & 3);
      // exact reference rounding: (z_sq - 2*p) + e_sq  (2*p exact in fp)
      float dsc = (zs - 2.0f * acc[i][j]) + esq[col];
      u64_t kk = ((u64_t)f32_key(dsc) << 32) | (unsigned)col;
      if (kk < best) best = kk;
    }
    mb[row][tx] = best;
  }
  __syncthreads();
  {
    u64_t b = mb[tid][0];
#pragma unroll
    for (int t2 = 1; t2 < 16; ++t2) {
      u64_t v = mb[tid][t2];
      if (v < b) b = v;
    }
    atomicMin(&keys[arow + tid], b);
  }
}

// sum of squares per row (256 cols); block = 4 rows x 64 lanes
__global__ __launch_bounds__(256) void rowsq(const float* __restrict__ src,
                                             float* __restrict__ dst, int rows) {
  const int sub = threadIdx.x >> 6;
  const int lane = threadIdx.x & 63;
  const int r = blockIdx.x * 4 + sub;
  if (r >= rows) return;
  const float* p = src + (size_t)r * 256;
  float s = 0.f;
#pragma unroll
  for (int j = 0; j < 4; ++j) {
    float v = p[lane + 64 * j];
    s += v * v;
  }
#pragma unroll
  for (int off = 32; off > 0; off >>= 1) s += __shfl_down(s, off, 64);
  if (lane == 0) dst[r] = s;
}

__global__ __launch_bounds__(256) void init_keys(u64_t* __restrict__ keys) {
  keys[(size_t)blockIdx.x * 256 + threadIdx.x] = ~0ull;
}

// per row: idx from key, write z_latent = z + (e - z), quant-loss partial sums
__global__ __launch_bounds__(256) void gather_quant(
    const u64_t* __restrict__ keys, const float* __restrict__ emb,
    const float* __restrict__ z_e, float* __restrict__ zlat,
    int* __restrict__ idx_out, float* __restrict__ qparts) {
  const int sub = threadIdx.x >> 6;
  const int lane = threadIdx.x & 63;
  const int r = blockIdx.x * 4 + sub;
  const int idx = (int)(keys[r] & 0xFFFFFFFFull);
  if (lane == 0) idx_out[r] = idx;
  float s = 0.f;
#pragma unroll
  for (int j = 0; j < 4; ++j) {
    const int d = lane + 64 * j;
    float e = emb[(size_t)idx * 256 + d];
    float z = z_e[(size_t)r * 256 + d];
    float df = e - z;
    s += df * df;
    zlat[(size_t)r * 256 + d] = z + df;  // fl(z_e + fl(z_q - z_e)) — exact ref order
  }
#pragma unroll
  for (int off = 32; off > 0; off >>= 1) s += __shfl_down(s, off, 64);
  __shared__ float red[4];
  if (lane == 0) red[sub] = s;
  __syncthreads();
  if (threadIdx.x == 0) qparts[blockIdx.x] = (red[0] + red[1]) + (red[2] + red[3]);
}

__global__ __launch_bounds__(256) void final_loss(
    const float* __restrict__ qparts, int nq,
    const float* __restrict__ rparts, int nr, float* __restrict__ out) {
  const int tid = threadIdx.x;
  double sq = 0.0, sr = 0.0;
  for (int i = tid; i < nq; i += 256) sq += (double)qparts[i];
  for (int i = tid; i < nr; i += 256) sr += (double)rparts[i];
  __shared__ double bq[256], br[256];
  bq[tid] = sq;
  br[tid] = sr;
  __syncthreads();
  for (int off = 128; off > 0; off >>= 1) {
    if (tid < off) {
      bq[tid] += bq[tid + off];
      br[tid] += br[tid + off];
    }
    __syncthreads();
  }
  if (tid == 0) {
    double qm = bq[0] / ((double)NROWS * 256.0);
    double rm = br[0] / ((double)NROWS * 512.0);
    out[(size_t)NROWS * 256] = (float)(rm + 1.25 * qm);  // recon + (1+BETA)*quant
  }
}

extern "C" void kernel_launch(void* const* d_in, const int* in_sizes, int n_in,
                              void* d_out, int out_size, void* d_ws, size_t ws_size,
                              hipStream_t stream) {
  const float* x   = (const float*)d_in[0];
  const float* ew1 = (const float*)d_in[1];
  const float* eb1 = (const float*)d_in[2];
  const float* ew2 = (const float*)d_in[3];
  const float* eb2 = (const float*)d_in[4];
  const float* ew3 = (const float*)d_in[5];
  const float* eb3 = (const float*)d_in[6];
  const float* dw1 = (const float*)d_in[7];
  const float* db1 = (const float*)d_in[8];
  const float* dw2 = (const float*)d_in[9];
  const float* db2 = (const float*)d_in[10];
  const float* dw3 = (const float*)d_in[11];
  const float* db3 = (const float*)d_in[12];
  const float* emb = (const float*)d_in[13];

  char* ws = (char*)d_ws;
  float* h1     = (float*)(ws);                    // N x 64   (reused as dec h2)
  float* h2     = (float*)(ws + 33554432ull);      // N x 128  (reused as dec h1)
  float* z_e    = (float*)(ws + 100663296ull);     // N x 256
  float* zsq    = (float*)(ws + 234881024ull);     // N
  float* esq    = (float*)(ws + 235405312ull);     // KE
  u64_t* keys   = (u64_t*)(ws + 235413504ull);     // N
  int* idx      = (int*)(ws + 236462080ull);       // N
  float* qparts = (float*)(ws + 236986368ull);     // N/4 = 32768
  float* rparts = (float*)(ws + 237117440ull);     // 1024*4 = 4096

  float* out = (float*)d_out;

  dim3 blk(256);

  // encoder: 512 -> 64 -> 128 -> 256  (all unchanged -> bit-exact z_e)
  gemm64<0><<<dim3(NROWS / 64, 1), blk, 0, stream>>>(x, ew1, eb1, h1, NROWS, 64, 512,
      nullptr);
  gemm128<0><<<dim3(NROWS / 128, 1), blk, 0, stream>>>(h1, ew2, eb2, h2,
      128, 64, nullptr, nullptr, nullptr);
  gemm128<0><<<dim3(NROWS / 128, 2), blk, 0, stream>>>(h2, ew3, eb3, z_e,
      256, 128, nullptr, nullptr, nullptr);

  rowsq<<<dim3(NROWS / 4), blk, 0, stream>>>(z_e, zsq, NROWS);
  rowsq<<<dim3(KE / 4), blk, 0, stream>>>(emb, esq, KE);
  init_keys<<<dim3(NROWS / 256), blk, 0, stream>>>(keys);

  // distances + argmin: 256x128 blocks, 16x8/thread, XCD-swizzled grid
  dist16x8<<<dim3((NROWS / 256) * (KE / 128)), blk, 0, stream>>>(z_e, emb, zsq, esq, keys);

  gather_quant<<<dim3(NROWS / 4), blk, 0, stream>>>(keys, emb, z_e, out, idx, qparts);

  // decoder: 256 -> 128 -> 64 -> 512 (loss-only path, 2% threshold)
  gemm128<1><<<dim3(NROWS / 128, 1), blk, 0, stream>>>(emb, dw1, db1, h2,
      128, 256, idx, nullptr, nullptr);
  gemm64<0><<<dim3(NROWS / 64, 1), blk, 0, stream>>>(h2, dw2, db2, h1, NROWS, 64, 128,
      nullptr);
  gemm128<2><<<dim3(NROWS / 128, 4), blk, 0, stream>>>(h1, dw3, db3, nullptr,
      512, 64, nullptr, x, rparts);

  final_loss<<<dim3(1), blk, 0, stream>>>(qparts, NROWS / 4, rparts, 4096, out);
}

// Round 8
// 4568.836 us; speedup vs baseline: 3.9649x; 1.0382x over previous
//
#include <hip/hip_runtime.h>

#define NROWS 131072
#define KE 2048

typedef unsigned long long u64_t;

__device__ __forceinline__ unsigned f32_key(float f) {
  unsigned u = __float_as_uint(f);
  return (u & 0x80000000u) ? ~u : (u | 0x80000000u);
}

// ---------------------------------------------------------------------------
// 64x64 tile f32 GEMM (UNCHANGED — enc1/dec2). MODE 0 only.
// ---------------------------------------------------------------------------
template <int MODE>
__global__ __launch_bounds__(256) void gemm64(
    const float* __restrict__ A, const float* __restrict__ B,
    const float* __restrict__ bias, float* __restrict__ C,
    int M, int N, int K,
    const int* __restrict__ gidx) {
  __shared__ __align__(16) float As[16][68];
  __shared__ __align__(16) float Bs[16][68];

  const int tid = threadIdx.x;
  const int tx = tid & 15;
  const int ty = tid >> 4;
  const int arow = blockIdx.x * 64;
  const int bcol = blockIdx.y * 64;

  const int lr = tid >> 2;
  const int lc = (tid & 3) * 4;
  int ga = arow + lr;
  if (MODE == 1) ga = gidx[ga];
  const float* Ap = A + (size_t)ga * K + lc;

  const int bkr = tid >> 4;
  const int bc4 = (tid & 15) * 4;
  const float* Bp = B + (size_t)bkr * N + bcol + bc4;

  float acc[4][4] = {};

  for (int kt = 0; kt < K; kt += 16) {
    float4 av = *reinterpret_cast<const float4*>(Ap);
    As[lc + 0][lr] = av.x;
    As[lc + 1][lr] = av.y;
    As[lc + 2][lr] = av.z;
    As[lc + 3][lr] = av.w;
    float4 bv = *reinterpret_cast<const float4*>(Bp);
    *reinterpret_cast<float4*>(&Bs[bkr][bc4]) = bv;
    Bp += (size_t)16 * N;
    Ap += 16;
    __syncthreads();
#pragma unroll
    for (int k = 0; k < 16; ++k) {
      float4 a = *reinterpret_cast<const float4*>(&As[k][ty * 4]);
      float4 b = *reinterpret_cast<const float4*>(&Bs[k][tx * 4]);
      acc[0][0] += a.x * b.x; acc[0][1] += a.x * b.y; acc[0][2] += a.x * b.z; acc[0][3] += a.x * b.w;
      acc[1][0] += a.y * b.x; acc[1][1] += a.y * b.y; acc[1][2] += a.y * b.z; acc[1][3] += a.y * b.w;
      acc[2][0] += a.z * b.x; acc[2][1] += a.z * b.y; acc[2][2] += a.z * b.z; acc[2][3] += a.z * b.w;
      acc[3][0] += a.w * b.x; acc[3][1] += a.w * b.y; acc[3][2] += a.w * b.z; acc[3][3] += a.w * b.w;
    }
    __syncthreads();
  }

#pragma unroll
  for (int i = 0; i < 4; ++i) {
    const int row = arow + ty * 4 + i;
    float4 v;
    v.x = fmaxf(acc[i][0] + bias[bcol + tx * 4 + 0], 0.f);
    v.y = fmaxf(acc[i][1] + bias[bcol + tx * 4 + 1], 0.f);
    v.z = fmaxf(acc[i][2] + bias[bcol + tx * 4 + 2], 0.f);
    v.w = fmaxf(acc[i][3] + bias[bcol + tx * 4 + 3], 0.f);
    *reinterpret_cast<float4*>(&C[(size_t)row * N + bcol + tx * 4]) = v;
  }
}

// ---------------------------------------------------------------------------
// 128x128 tile f32 GEMM (UNCHANGED — enc2/enc3/dec1/dec3). Modes 0/1/2.
// ---------------------------------------------------------------------------
template <int MODE>
__global__ __launch_bounds__(256) void gemm128(
    const float* __restrict__ A, const float* __restrict__ B,
    const float* __restrict__ bias, float* __restrict__ C,
    int N, int K,
    const int* __restrict__ gidx,
    const float* __restrict__ X,
    float* __restrict__ parts) {
  __shared__ __align__(16) char smem[17408];
  float (*As)[132] = (float(*)[132])smem;
  float (*Bs)[132] = (float(*)[132])(smem + 8448);

  const int tid = threadIdx.x;
  const int tx = tid & 15;
  const int ty = tid >> 4;
  const int arow = blockIdx.x * 128;
  const int bcol = blockIdx.y * 128;

  const int r0 = tid >> 2;
  const int r1 = r0 + 64;
  const int lc = (tid & 3) * 4;
  int ga0 = arow + r0, ga1 = arow + r1;
  if (MODE == 1) { ga0 = gidx[ga0]; ga1 = gidx[ga1]; }
  const float* Ap0 = A + (size_t)ga0 * K + lc;
  const float* Ap1 = A + (size_t)ga1 * K + lc;

  const int bk0 = tid >> 5;
  const int bc0 = (tid & 31) * 4;
  const float* Bp0 = B + (size_t)bk0 * N + bcol + bc0;
  const float* Bp1 = B + (size_t)(bk0 + 8) * N + bcol + bc0;

  float acc[8][8] = {};

  for (int kt = 0; kt < K; kt += 16) {
    float4 a0 = *reinterpret_cast<const float4*>(Ap0);
    float4 a1 = *reinterpret_cast<const float4*>(Ap1);
    As[lc + 0][r0] = a0.x; As[lc + 1][r0] = a0.y; As[lc + 2][r0] = a0.z; As[lc + 3][r0] = a0.w;
    As[lc + 0][r1] = a1.x; As[lc + 1][r1] = a1.y; As[lc + 2][r1] = a1.z; As[lc + 3][r1] = a1.w;
    float4 b0 = *reinterpret_cast<const float4*>(Bp0);
    float4 b1 = *reinterpret_cast<const float4*>(Bp1);
    *reinterpret_cast<float4*>(&Bs[bk0][bc0]) = b0;
    *reinterpret_cast<float4*>(&Bs[bk0 + 8][bc0]) = b1;
    Bp0 += (size_t)16 * N; Bp1 += (size_t)16 * N;
    Ap0 += 16; Ap1 += 16;
    __syncthreads();
#pragma unroll
    for (int k = 0; k < 16; ++k) {
      float4 av0 = *reinterpret_cast<const float4*>(&As[k][ty * 4]);
      float4 av1 = *reinterpret_cast<const float4*>(&As[k][64 + ty * 4]);
      float4 bv0 = *reinterpret_cast<const float4*>(&Bs[k][tx * 4]);
      float4 bv1 = *reinterpret_cast<const float4*>(&Bs[k][64 + tx * 4]);
      const float a[8] = {av0.x, av0.y, av0.z, av0.w, av1.x, av1.y, av1.z, av1.w};
      const float b[8] = {bv0.x, bv0.y, bv0.z, bv0.w, bv1.x, bv1.y, bv1.z, bv1.w};
#pragma unroll
      for (int i = 0; i < 8; ++i)
#pragma unroll
        for (int j = 0; j < 8; ++j) acc[i][j] += a[i] * b[j];
    }
    __syncthreads();
  }

  if (MODE == 0 || MODE == 1) {
#pragma unroll
    for (int i = 0; i < 8; ++i) {
      const int row = arow + (i >> 2) * 64 + ty * 4 + (i & 3);
      const int c0 = bcol + tx * 4;
      const int c1 = bcol + 64 + tx * 4;
      float4 v0, v1;
      v0.x = fmaxf(acc[i][0] + bias[c0 + 0], 0.f);
      v0.y = fmaxf(acc[i][1] + bias[c0 + 1], 0.f);
      v0.z = fmaxf(acc[i][2] + bias[c0 + 2], 0.f);
      v0.w = fmaxf(acc[i][3] + bias[c0 + 3], 0.f);
      v1.x = fmaxf(acc[i][4] + bias[c1 + 0], 0.f);
      v1.y = fmaxf(acc[i][5] + bias[c1 + 1], 0.f);
      v1.z = fmaxf(acc[i][6] + bias[c1 + 2], 0.f);
      v1.w = fmaxf(acc[i][7] + bias[c1 + 3], 0.f);
      *reinterpret_cast<float4*>(&C[(size_t)row * N + c0]) = v0;
      *reinterpret_cast<float4*>(&C[(size_t)row * N + c1]) = v1;
    }
  } else if (MODE == 2) {
    float local = 0.f;
#pragma unroll
    for (int i = 0; i < 8; ++i) {
      const int row = arow + (i >> 2) * 64 + ty * 4 + (i & 3);
#pragma unroll
      for (int j = 0; j < 8; ++j) {
        const int col = bcol + (j >> 2) * 64 + tx * 4 + (j & 3);
        float v = fmaxf(acc[i][j] + bias[col], 0.f);
        float d = v - X[(size_t)row * N + col];
        local += d * d;
      }
    }
    float* rbuf = (float*)smem;
    rbuf[tid] = local;
    __syncthreads();
    for (int off = 128; off > 0; off >>= 1) {
      if (tid < off) rbuf[tid] += rbuf[tid + off];
      __syncthreads();
    }
    if (tid == 0) parts[blockIdx.y * gridDim.x + blockIdx.x] = rbuf[0];
  }
}

// ---------------------------------------------------------------------------
// dist16x8: distance + argmin. Tile 256 rows x 128 cols, 256 threads,
// per-thread 16 rows x 8 cols (128 acc) in 4x2 quadrants of 4.
// Round-8 change: __builtin_amdgcn_sched_barrier(0) after every 2 k-steps of
// the FMA phase. Round 7 (VGPR=256, WRITE_SIZE 7.8 GB) showed the scheduler
// hoisting ds_reads across the 16-deep unrolled k-loop, inflating live
// registers past the 256 ArchVGPR ceiling and spilling ~60 to scratch.
// Bounding the hoisting window caps live frags at one 2-k group:
// 128 acc + 24 staging + ~48 frag + addr ~= 212 < 256.
// Schedule: global loads at iter top (hidden under FMA phase), reg->LDS
// writes after compute, ONE barrier per tile.
// k accumulation strictly ascending (t outer, k inner) -> bit-identical
// scores -> argmin identical to reference.
// ---------------------------------------------------------------------------
__global__ __launch_bounds__(256, 1) void dist16x8(
    const float* __restrict__ A,   // z_e [NROWS][256]
    const float* __restrict__ B,   // emb [KE][256]
    const float* __restrict__ zsq,
    const float* __restrict__ esq,
    u64_t* __restrict__ keys) {
  // per buffer: As 16x260 f32 (16640 B) + Bs 16x132 f32 (8448 B) = 25088 B
  __shared__ __align__(16) char smem[50176];

  const int tid = threadIdx.x;
  const int tx = tid & 15;
  const int ty = tid >> 4;

  // XCD-aware block swizzle: 8192 blocks; dispatch round-robins d%8 over XCDs.
  const int d = blockIdx.x;
  const int xcd = d & 7;
  const int slot = d >> 3;
  const int row_tile = xcd + 8 * (slot >> 4);  // 0..511
  const int col_tile = slot & 15;              // 0..15
  const int arow = row_tile * 256;
  const int bcol = col_tile * 128;

  // staging mapping: 4 lanes per row, 16B each (coalesced 64B per row-segment)
  const int r0 = tid >> 2;        // 0..63
  const int lc = (tid & 3) * 4;   // 0,4,8,12
  const float* ApG = A + (size_t)(arow + r0) * 256 + lc;
  const float* BpG = B + (size_t)(bcol + r0) * 256 + lc;

  float4 sa0, sa1, sa2, sa3, sb0, sb1;

#define DLOAD(kt)                                              \
  do {                                                         \
    sa0 = *reinterpret_cast<const float4*>(ApG + (kt));        \
    sa1 = *reinterpret_cast<const float4*>(ApG + 16384 + (kt));\
    sa2 = *reinterpret_cast<const float4*>(ApG + 32768 + (kt));\
    sa3 = *reinterpret_cast<const float4*>(ApG + 49152 + (kt));\
    sb0 = *reinterpret_cast<const float4*>(BpG + (kt));        \
    sb1 = *reinterpret_cast<const float4*>(BpG + 16384 + (kt));\
  } while (0)

#define DWRITE(buf)                                            \
  do {                                                         \
    float* As = (float*)(buf);                                 \
    float* Bs = (float*)((buf) + 16640);                       \
    As[(lc + 0) * 260 + r0] = sa0.x; As[(lc + 1) * 260 + r0] = sa0.y; \
    As[(lc + 2) * 260 + r0] = sa0.z; As[(lc + 3) * 260 + r0] = sa0.w; \
    As[(lc + 0) * 260 + r0 + 64] = sa1.x; As[(lc + 1) * 260 + r0 + 64] = sa1.y; \
    As[(lc + 2) * 260 + r0 + 64] = sa1.z; As[(lc + 3) * 260 + r0 + 64] = sa1.w; \
    As[(lc + 0) * 260 + r0 + 128] = sa2.x; As[(lc + 1) * 260 + r0 + 128] = sa2.y; \
    As[(lc + 2) * 260 + r0 + 128] = sa2.z; As[(lc + 3) * 260 + r0 + 128] = sa2.w; \
    As[(lc + 0) * 260 + r0 + 192] = sa3.x; As[(lc + 1) * 260 + r0 + 192] = sa3.y; \
    As[(lc + 2) * 260 + r0 + 192] = sa3.z; As[(lc + 3) * 260 + r0 + 192] = sa3.w; \
    Bs[(lc + 0) * 132 + r0] = sb0.x; Bs[(lc + 1) * 132 + r0] = sb0.y; \
    Bs[(lc + 2) * 132 + r0] = sb0.z; Bs[(lc + 3) * 132 + r0] = sb0.w; \
    Bs[(lc + 0) * 132 + r0 + 64] = sb1.x; Bs[(lc + 1) * 132 + r0 + 64] = sb1.y; \
    Bs[(lc + 2) * 132 + r0 + 64] = sb1.z; Bs[(lc + 3) * 132 + r0 + 64] = sb1.w; \
  } while (0)

  float acc[16][8] = {};

  // prologue: stage tile 0 into buffer 0
  DLOAD(0);
  DWRITE(smem);

  for (int t = 0; t < 16; ++t) {
    if (t < 15) DLOAD((t + 1) * 16);   // VMEM in flight under compute
    __syncthreads();                    // buf[t&1] writes visible; buf[(t+1)&1] reads done
    {
      const char* buf = smem + (size_t)(t & 1) * 25088;
      const float* As = (const float*)buf;
      const float* Bs = (const float*)(buf + 16640);
#pragma unroll
      for (int kg = 0; kg < 8; ++kg) {
#pragma unroll
        for (int kk = 0; kk < 2; ++kk) {
          const int k = kg * 2 + kk;
          float4 a0 = *reinterpret_cast<const float4*>(As + k * 260 + ty * 4);
          float4 a1 = *reinterpret_cast<const float4*>(As + k * 260 + 64 + ty * 4);
          float4 a2 = *reinterpret_cast<const float4*>(As + k * 260 + 128 + ty * 4);
          float4 a3 = *reinterpret_cast<const float4*>(As + k * 260 + 192 + ty * 4);
          float4 b0 = *reinterpret_cast<const float4*>(Bs + k * 132 + tx * 4);
          float4 b1 = *reinterpret_cast<const float4*>(Bs + k * 132 + 64 + tx * 4);
          const float a[16] = {a0.x, a0.y, a0.z, a0.w, a1.x, a1.y, a1.z, a1.w,
                               a2.x, a2.y, a2.z, a2.w, a3.x, a3.y, a3.z, a3.w};
          const float b[8] = {b0.x, b0.y, b0.z, b0.w, b1.x, b1.y, b1.z, b1.w};
#pragma unroll
          for (int i = 0; i < 16; ++i)
#pragma unroll
            for (int j = 0; j < 8; ++j) acc[i][j] += a[i] * b[j];
        }
        // bound scheduler hoisting window -> cap live fragment registers
        __builtin_amdgcn_sched_barrier(0);
      }
    }
    if (t < 15) DWRITE(smem + (size_t)((t + 1) & 1) * 25088);
  }
  __syncthreads();  // before smem reuse as mb

#undef DLOAD
#undef DWRITE

  // epilogue: scores + per-block argmin (exact reference rounding)
  u64_t (*mb)[17] = (u64_t(*)[17])smem;  // 256 x 17 x 8 = 34816 B
#pragma unroll
  for (int i = 0; i < 16; ++i) {
    const int row = (i >> 2) * 64 + ty * 4 + (i & 3);
    const float zs = zsq[arow + row];
    u64_t best = ~0ull;
#pragma unroll
    for (int j = 0; j < 8; ++j) {
      const int col = bcol + (j >> 2) * 64 + tx * 4 + (j & 3);
      // exact reference rounding: (z_sq - 2*p) + e_sq  (2*p exact in fp)
      float dsc = (zs - 2.0f * acc[i][j]) + esq[col];
      u64_t kk = ((u64_t)f32_key(dsc) << 32) | (unsigned)col;
      if (kk < best) best = kk;
    }
    mb[row][tx] = best;
  }
  __syncthreads();
  {
    u64_t b = mb[tid][0];
#pragma unroll
    for (int t2 = 1; t2 < 16; ++t2) {
      u64_t v = mb[tid][t2];
      if (v < b) b = v;
    }
    atomicMin(&keys[arow + tid], b);
  }
}

// sum of squares per row (256 cols); block = 4 rows x 64 lanes
__global__ __launch_bounds__(256) void rowsq(const float* __restrict__ src,
                                             float* __restrict__ dst, int rows) {
  const int sub = threadIdx.x >> 6;
  const int lane = threadIdx.x & 63;
  const int r = blockIdx.x * 4 + sub;
  if (r >= rows) return;
  const float* p = src + (size_t)r * 256;
  float s = 0.f;
#pragma unroll
  for (int j = 0; j < 4; ++j) {
    float v = p[lane + 64 * j];
    s += v * v;
  }
#pragma unroll
  for (int off = 32; off > 0; off >>= 1) s += __shfl_down(s, off, 64);
  if (lane == 0) dst[r] = s;
}

__global__ __launch_bounds__(256) void init_keys(u64_t* __restrict__ keys) {
  keys[(size_t)blockIdx.x * 256 + threadIdx.x] = ~0ull;
}

// per row: idx from key, write z_latent = z + (e - z), quant-loss partial sums
__global__ __launch_bounds__(256) void gather_quant(
    const u64_t* __restrict__ keys, const float* __restrict__ emb,
    const float* __restrict__ z_e, float* __restrict__ zlat,
    int* __restrict__ idx_out, float* __restrict__ qparts) {
  const int sub = threadIdx.x >> 6;
  const int lane = threadIdx.x & 63;
  const int r = blockIdx.x * 4 + sub;
  const int idx = (int)(keys[r] & 0xFFFFFFFFull);
  if (lane == 0) idx_out[r] = idx;
  float s = 0.f;
#pragma unroll
  for (int j = 0; j < 4; ++j) {
    const int d = lane + 64 * j;
    float e = emb[(size_t)idx * 256 + d];
    float z = z_e[(size_t)r * 256 + d];
    float df = e - z;
    s += df * df;
    zlat[(size_t)r * 256 + d] = z + df;  // fl(z_e + fl(z_q - z_e)) — exact ref order
  }
#pragma unroll
  for (int off = 32; off > 0; off >>= 1) s += __shfl_down(s, off, 64);
  __shared__ float red[4];
  if (lane == 0) red[sub] = s;
  __syncthreads();
  if (threadIdx.x == 0) qparts[blockIdx.x] = (red[0] + red[1]) + (red[2] + red[3]);
}

__global__ __launch_bounds__(256) void final_loss(
    const float* __restrict__ qparts, int nq,
    const float* __restrict__ rparts, int nr, float* __restrict__ out) {
  const int tid = threadIdx.x;
  double sq = 0.0, sr = 0.0;
  for (int i = tid; i < nq; i += 256) sq += (double)qparts[i];
  for (int i = tid; i < nr; i += 256) sr += (double)rparts[i];
  __shared__ double bq[256], br[256];
  bq[tid] = sq;
  br[tid] = sr;
  __syncthreads();
  for (int off = 128; off > 0; off >>= 1) {
    if (tid < off) {
      bq[tid] += bq[tid + off];
      br[tid] += br[tid + off];
    }
    __syncthreads();
  }
  if (tid == 0) {
    double qm = bq[0] / ((double)NROWS * 256.0);
    double rm = br[0] / ((double)NROWS * 512.0);
    out[(size_t)NROWS * 256] = (float)(rm + 1.25 * qm);  // recon + (1+BETA)*quant
  }
}

extern "C" void kernel_launch(void* const* d_in, const int* in_sizes, int n_in,
                              void* d_out, int out_size, void* d_ws, size_t ws_size,
                              hipStream_t stream) {
  const float* x   = (const float*)d_in[0];
  const float* ew1 = (const float*)d_in[1];
  const float* eb1 = (const float*)d_in[2];
  const float* ew2 = (const float*)d_in[3];
  const float* eb2 = (const float*)d_in[4];
  const float* ew3 = (const float*)d_in[5];
  const float* eb3 = (const float*)d_in[6];
  const float* dw1 = (const float*)d_in[7];
  const float* db1 = (const float*)d_in[8];
  const float* dw2 = (const float*)d_in[9];
  const float* db2 = (const float*)d_in[10];
  const float* dw3 = (const float*)d_in[11];
  const float* db3 = (const float*)d_in[12];
  const float* emb = (const float*)d_in[13];

  char* ws = (char*)d_ws;
  float* h1     = (float*)(ws);                    // N x 64   (reused as dec h2)
  float* h2     = (float*)(ws + 33554432ull);      // N x 128  (reused as dec h1)
  float* z_e    = (float*)(ws + 100663296ull);     // N x 256
  float* zsq    = (float*)(ws + 234881024ull);     // N
  float* esq    = (float*)(ws + 235405312ull);     // KE
  u64_t* keys   = (u64_t*)(ws + 235413504ull);     // N
  int* idx      = (int*)(ws + 236462080ull);       // N
  float* qparts = (float*)(ws + 236986368ull);     // N/4 = 32768
  float* rparts = (float*)(ws + 237117440ull);     // 1024*4 = 4096

  float* out = (float*)d_out;

  dim3 blk(256);

  // encoder: 512 -> 64 -> 128 -> 256  (all unchanged -> bit-exact z_e)
  gemm64<0><<<dim3(NROWS / 64, 1), blk, 0, stream>>>(x, ew1, eb1, h1, NROWS, 64, 512,
      nullptr);
  gemm128<0><<<dim3(NROWS / 128, 1), blk, 0, stream>>>(h1, ew2, eb2, h2,
      128, 64, nullptr, nullptr, nullptr);
  gemm128<0><<<dim3(NROWS / 128, 2), blk, 0, stream>>>(h2, ew3, eb3, z_e,
      256, 128, nullptr, nullptr, nullptr);

  rowsq<<<dim3(NROWS / 4), blk, 0, stream>>>(z_e, zsq, NROWS);
  rowsq<<<dim3(KE / 4), blk, 0, stream>>>(emb, esq, KE);
  init_keys<<<dim3(NROWS / 256), blk, 0, stream>>>(keys);

  // distances + argmin: 256x128 blocks, 16x8/thread, XCD-swizzled grid
  dist16x8<<<dim3((NROWS / 256) * (KE / 128)), blk, 0, stream>>>(z_e, emb, zsq, esq, keys);

  gather_quant<<<dim3(NROWS / 4), blk, 0, stream>>>(keys, emb, z_e, out, idx, qparts);

  // decoder: 256 -> 128 -> 64 -> 512 (loss-only path, 2% threshold)
  gemm128<1><<<dim3(NROWS / 128, 1), blk, 0, stream>>>(emb, dw1, db1, h2,
      128, 256, idx, nullptr, nullptr);
  gemm64<0><<<dim3(NROWS / 64, 1), blk, 0, stream>>>(h2, dw2, db2, h1, NROWS, 64, 128,
      nullptr);
  gemm128<2><<<dim3(NROWS / 128, 4), blk, 0, stream>>>(h1, dw3, db3, nullptr,
      512, 64, nullptr, x, rparts);

  final_loss<<<dim3(1), blk, 0, stream>>>(qparts, NROWS / 4, rparts, 4096, out);
}

// Round 9
// 2924.676 us; speedup vs baseline: 6.1939x; 1.5622x over previous
//
#include <hip/hip_runtime.h>

#define NROWS 131072
#define KE 2048

typedef unsigned long long u64_t;
typedef __attribute__((ext_vector_type(8))) short bf16x8;
typedef __attribute__((ext_vector_type(4))) float f32x4;

__device__ __forceinline__ unsigned f32_key(float f) {
  unsigned u = __float_as_uint(f);
  return (u & 0x80000000u) ? ~u : (u | 0x80000000u);
}

// ---------------------------------------------------------------------------
// 64x64 tile f32 GEMM (UNCHANGED — enc1/dec2). MODE 0 only.
// ---------------------------------------------------------------------------
template <int MODE>
__global__ __launch_bounds__(256) void gemm64(
    const float* __restrict__ A, const float* __restrict__ B,
    const float* __restrict__ bias, float* __restrict__ C,
    int M, int N, int K,
    const int* __restrict__ gidx) {
  __shared__ __align__(16) float As[16][68];
  __shared__ __align__(16) float Bs[16][68];

  const int tid = threadIdx.x;
  const int tx = tid & 15;
  const int ty = tid >> 4;
  const int arow = blockIdx.x * 64;
  const int bcol = blockIdx.y * 64;

  const int lr = tid >> 2;
  const int lc = (tid & 3) * 4;
  int ga = arow + lr;
  if (MODE == 1) ga = gidx[ga];
  const float* Ap = A + (size_t)ga * K + lc;

  const int bkr = tid >> 4;
  const int bc4 = (tid & 15) * 4;
  const float* Bp = B + (size_t)bkr * N + bcol + bc4;

  float acc[4][4] = {};

  for (int kt = 0; kt < K; kt += 16) {
    float4 av = *reinterpret_cast<const float4*>(Ap);
    As[lc + 0][lr] = av.x;
    As[lc + 1][lr] = av.y;
    As[lc + 2][lr] = av.z;
    As[lc + 3][lr] = av.w;
    float4 bv = *reinterpret_cast<const float4*>(Bp);
    *reinterpret_cast<float4*>(&Bs[bkr][bc4]) = bv;
    Bp += (size_t)16 * N;
    Ap += 16;
    __syncthreads();
#pragma unroll
    for (int k = 0; k < 16; ++k) {
      float4 a = *reinterpret_cast<const float4*>(&As[k][ty * 4]);
      float4 b = *reinterpret_cast<const float4*>(&Bs[k][tx * 4]);
      acc[0][0] += a.x * b.x; acc[0][1] += a.x * b.y; acc[0][2] += a.x * b.z; acc[0][3] += a.x * b.w;
      acc[1][0] += a.y * b.x; acc[1][1] += a.y * b.y; acc[1][2] += a.y * b.z; acc[1][3] += a.y * b.w;
      acc[2][0] += a.z * b.x; acc[2][1] += a.z * b.y; acc[2][2] += a.z * b.z; acc[2][3] += a.z * b.w;
      acc[3][0] += a.w * b.x; acc[3][1] += a.w * b.y; acc[3][2] += a.w * b.z; acc[3][3] += a.w * b.w;
    }
    __syncthreads();
  }

#pragma unroll
  for (int i = 0; i < 4; ++i) {
    const int row = arow + ty * 4 + i;
    float4 v;
    v.x = fmaxf(acc[i][0] + bias[bcol + tx * 4 + 0], 0.f);
    v.y = fmaxf(acc[i][1] + bias[bcol + tx * 4 + 1], 0.f);
    v.z = fmaxf(acc[i][2] + bias[bcol + tx * 4 + 2], 0.f);
    v.w = fmaxf(acc[i][3] + bias[bcol + tx * 4 + 3], 0.f);
    *reinterpret_cast<float4*>(&C[(size_t)row * N + bcol + tx * 4]) = v;
  }
}

// ---------------------------------------------------------------------------
// 128x128 tile f32 GEMM (UNCHANGED — enc2/enc3/dec1/dec3). Modes 0/1/2.
// ---------------------------------------------------------------------------
template <int MODE>
__global__ __launch_bounds__(256) void gemm128(
    const float* __restrict__ A, const float* __restrict__ B,
    const float* __restrict__ bias, float* __restrict__ C,
    int N, int K,
    const int* __restrict__ gidx,
    const float* __restrict__ X,
    float* __restrict__ parts) {
  __shared__ __align__(16) char smem[17408];
  float (*As)[132] = (float(*)[132])smem;
  float (*Bs)[132] = (float(*)[132])(smem + 8448);

  const int tid = threadIdx.x;
  const int tx = tid & 15;
  const int ty = tid >> 4;
  const int arow = blockIdx.x * 128;
  const int bcol = blockIdx.y * 128;

  const int r0 = tid >> 2;
  const int r1 = r0 + 64;
  const int lc = (tid & 3) * 4;
  int ga0 = arow + r0, ga1 = arow + r1;
  if (MODE == 1) { ga0 = gidx[ga0]; ga1 = gidx[ga1]; }
  const float* Ap0 = A + (size_t)ga0 * K + lc;
  const float* Ap1 = A + (size_t)ga1 * K + lc;

  const int bk0 = tid >> 5;
  const int bc0 = (tid & 31) * 4;
  const float* Bp0 = B + (size_t)bk0 * N + bcol + bc0;
  const float* Bp1 = B + (size_t)(bk0 + 8) * N + bcol + bc0;

  float acc[8][8] = {};

  for (int kt = 0; kt < K; kt += 16) {
    float4 a0 = *reinterpret_cast<const float4*>(Ap0);
    float4 a1 = *reinterpret_cast<const float4*>(Ap1);
    As[lc + 0][r0] = a0.x; As[lc + 1][r0] = a0.y; As[lc + 2][r0] = a0.z; As[lc + 3][r0] = a0.w;
    As[lc + 0][r1] = a1.x; As[lc + 1][r1] = a1.y; As[lc + 2][r1] = a1.z; As[lc + 3][r1] = a1.w;
    float4 b0 = *reinterpret_cast<const float4*>(Bp0);
    float4 b1 = *reinterpret_cast<const float4*>(Bp1);
    *reinterpret_cast<float4*>(&Bs[bk0][bc0]) = b0;
    *reinterpret_cast<float4*>(&Bs[bk0 + 8][bc0]) = b1;
    Bp0 += (size_t)16 * N; Bp1 += (size_t)16 * N;
    Ap0 += 16; Ap1 += 16;
    __syncthreads();
#pragma unroll
    for (int k = 0; k < 16; ++k) {
      float4 av0 = *reinterpret_cast<const float4*>(&As[k][ty * 4]);
      float4 av1 = *reinterpret_cast<const float4*>(&As[k][64 + ty * 4]);
      float4 bv0 = *reinterpret_cast<const float4*>(&Bs[k][tx * 4]);
      float4 bv1 = *reinterpret_cast<const float4*>(&Bs[k][64 + tx * 4]);
      const float a[8] = {av0.x, av0.y, av0.z, av0.w, av1.x, av1.y, av1.z, av1.w};
      const float b[8] = {bv0.x, bv0.y, bv0.z, bv0.w, bv1.x, bv1.y, bv1.z, bv1.w};
#pragma unroll
      for (int i = 0; i < 8; ++i)
#pragma unroll
        for (int j = 0; j < 8; ++j) acc[i][j] += a[i] * b[j];
    }
    __syncthreads();
  }

  if (MODE == 0 || MODE == 1) {
#pragma unroll
    for (int i = 0; i < 8; ++i) {
      const int row = arow + (i >> 2) * 64 + ty * 4 + (i & 3);
      const int c0 = bcol + tx * 4;
      const int c1 = bcol + 64 + tx * 4;
      float4 v0, v1;
      v0.x = fmaxf(acc[i][0] + bias[c0 + 0], 0.f);
      v0.y = fmaxf(acc[i][1] + bias[c0 + 1], 0.f);
      v0.z = fmaxf(acc[i][2] + bias[c0 + 2], 0.f);
      v0.w = fmaxf(acc[i][3] + bias[c0 + 3], 0.f);
      v1.x = fmaxf(acc[i][4] + bias[c1 + 0], 0.f);
      v1.y = fmaxf(acc[i][5] + bias[c1 + 1], 0.f);
      v1.z = fmaxf(acc[i][6] + bias[c1 + 2], 0.f);
      v1.w = fmaxf(acc[i][7] + bias[c1 + 3], 0.f);
      *reinterpret_cast<float4*>(&C[(size_t)row * N + c0]) = v0;
      *reinterpret_cast<float4*>(&C[(size_t)row * N + c1]) = v1;
    }
  } else if (MODE == 2) {
    float local = 0.f;
#pragma unroll
    for (int i = 0; i < 8; ++i) {
      const int row = arow + (i >> 2) * 64 + ty * 4 + (i & 3);
#pragma unroll
      for (int j = 0; j < 8; ++j) {
        const int col = bcol + (j >> 2) * 64 + tx * 4 + (j & 3);
        float v = fmaxf(acc[i][j] + bias[col], 0.f);
        float d = v - X[(size_t)row * N + col];
        local += d * d;
      }
    }
    float* rbuf = (float*)smem;
    rbuf[tid] = local;
    __syncthreads();
    for (int off = 128; off > 0; off >>= 1) {
      if (tid < off) rbuf[tid] += rbuf[tid + off];
      __syncthreads();
    }
    if (tid == 0) parts[blockIdx.y * gridDim.x + blockIdx.x] = rbuf[0];
  }
}

// f32 -> bf16 (RNE), 8 elems/thread
__global__ __launch_bounds__(256) void cvt_bf16(const float* __restrict__ src,
                                                unsigned short* __restrict__ dst, int n8) {
  const int i = blockIdx.x * 256 + threadIdx.x;
  if (i >= n8) return;
  const float4 v0 = *reinterpret_cast<const float4*>(src + (size_t)i * 8);
  const float4 v1 = *reinterpret_cast<const float4*>(src + (size_t)i * 8 + 4);
  const float f[8] = {v0.x, v0.y, v0.z, v0.w, v1.x, v1.y, v1.z, v1.w};
  unsigned short s[8];
#pragma unroll
  for (int j = 0; j < 8; ++j) {
    unsigned u = __float_as_uint(f[j]);
    u += 0x7FFFu + ((u >> 16) & 1u);
    s[j] = (unsigned short)(u >> 16);
  }
  uint4 o;
  o.x = (unsigned)s[0] | ((unsigned)s[1] << 16);
  o.y = (unsigned)s[2] | ((unsigned)s[3] << 16);
  o.z = (unsigned)s[4] | ((unsigned)s[5] << 16);
  o.w = (unsigned)s[6] | ((unsigned)s[7] << 16);
  *reinterpret_cast<uint4*>(dst + (size_t)i * 8) = o;
}

// ---------------------------------------------------------------------------
// dist_mfma: 128x128 tile, 4 waves x (32 rows x 128 cols), K=256.
// Fragments straight from global (no LDS, no barriers); e16 is L2-resident,
// z16 panel L2-hot via r6's XCD swizzle (verified bijective r6-r8).
// PASS 0: per-row min of bf-scores (u32 key atomicMin). Score = esq - 2*p_bf
// (zsq dropped: row-constant, irrelevant for ranking).
// PASS 1: qualify vs thresh key, then EXACT rescore (ascending-k f32 fma
// chain + (zs-2p)+esq, identical arithmetic to rounds 1-8) -> keys64.
// Margin bound guarantees every exact-argmin (incl. ties) qualifies.
// ---------------------------------------------------------------------------
template <int PASS>
__global__ __launch_bounds__(256) void dist_mfma(
    const unsigned short* __restrict__ z16, const unsigned short* __restrict__ e16,
    const float* __restrict__ zf, const float* __restrict__ ef,
    const float* __restrict__ zsq, const float* __restrict__ esq,
    unsigned* __restrict__ rowmin, const unsigned* __restrict__ thresh,
    u64_t* __restrict__ keys) {
  const int tid = threadIdx.x;
  const int l = tid & 63;
  const int w = tid >> 6;
  const int l15 = l & 15;
  const int lk = l >> 4;

  const int g = blockIdx.x;             // 16384 blocks
  const int xcd = g & 7;
  const int slot = g >> 3;
  const int row_tile = xcd + 8 * (slot >> 4);  // 0..1023
  const int col_tile = slot & 15;              // 0..15
  const int arow = row_tile * 128 + w * 32;
  const int bcol = col_tile * 128;

  // A frag: lane l -> z row (arow + l15), k = lk*8 + [0..7] (+32 per kb)
  const unsigned short* za = z16 + (size_t)(arow + l15) * 256 + lk * 8;
  // B frag: lane l -> emb row (bcol + fc*16 + l15), same k mapping
  const unsigned short* eb = e16 + (size_t)(bcol + l15) * 256 + lk * 8;

  f32x4 acc[2][8];
#pragma unroll
  for (int i = 0; i < 2; ++i)
#pragma unroll
    for (int j = 0; j < 8; ++j) acc[i][j] = (f32x4){0.f, 0.f, 0.f, 0.f};

#pragma unroll 1
  for (int kb = 0; kb < 8; ++kb) {
    const bf16x8 a0 = *reinterpret_cast<const bf16x8*>(za + kb * 32);
    const bf16x8 a1 = *reinterpret_cast<const bf16x8*>(za + 16 * 256 + kb * 32);
#pragma unroll
    for (int fc = 0; fc < 8; ++fc) {
      const bf16x8 b = *reinterpret_cast<const bf16x8*>(eb + (size_t)fc * 16 * 256 + kb * 32);
      acc[0][fc] = __builtin_amdgcn_mfma_f32_16x16x32_bf16(a0, b, acc[0][fc], 0, 0, 0);
      acc[1][fc] = __builtin_amdgcn_mfma_f32_16x16x32_bf16(a1, b, acc[1][fc], 0, 0, 0);
    }
  }

  float esqv[8];
#pragma unroll
  for (int fc = 0; fc < 8; ++fc) esqv[fc] = esq[bcol + fc * 16 + l15];

  if (PASS == 0) {
#pragma unroll
    for (int fr = 0; fr < 2; ++fr)
#pragma unroll
      for (int reg = 0; reg < 4; ++reg) {
        unsigned k = 0xFFFFFFFFu;
#pragma unroll
        for (int fc = 0; fc < 8; ++fc) {
          const float s = fmaf(-2.f, acc[fr][fc][reg], esqv[fc]);
          const unsigned kk = f32_key(s);
          if (kk < k) k = kk;
        }
#pragma unroll
        for (int m = 1; m < 16; m <<= 1) {
          const unsigned o = (unsigned)__shfl_xor((int)k, m, 64);
          if (o < k) k = o;
        }
        // D mapping (m89): col = lane&15, row = lk*4 + reg (within frag fr)
        if (l15 == 0) atomicMin(&rowmin[arow + fr * 16 + lk * 4 + reg], k);
      }
  } else {
    int qn = 0;
    int qv[64];  // scratch (dynamic idx) — cap 64 = checks/lane, cannot overflow
#pragma unroll
    for (int fr = 0; fr < 2; ++fr)
#pragma unroll
      for (int reg = 0; reg < 4; ++reg) {
        const int rowoff = fr * 16 + lk * 4 + reg;
        const unsigned tk = thresh[arow + rowoff];
#pragma unroll
        for (int fc = 0; fc < 8; ++fc) {
          const float s = fmaf(-2.f, acc[fr][fc][reg], esqv[fc]);
          if (f32_key(s) <= tk) qv[qn++] = (rowoff << 11) | (bcol + fc * 16 + l15);
        }
      }
    for (int c = 0; c < qn; ++c) {
      const int e = qv[c];
      const int row = arow + (e >> 11);
      const int col = e & 2047;
      const float* zp = zf + (size_t)row * 256;
      const float* ep = ef + (size_t)col * 256;
      float p = 0.f;
      for (int k4 = 0; k4 < 256; k4 += 4) {  // ascending-k fma chain == rounds 1-8
        const float4 zv = *reinterpret_cast<const float4*>(zp + k4);
        const float4 ev = *reinterpret_cast<const float4*>(ep + k4);
        p = fmaf(zv.x, ev.x, p);
        p = fmaf(zv.y, ev.y, p);
        p = fmaf(zv.z, ev.z, p);
        p = fmaf(zv.w, ev.w, p);
      }
      const float dsc = (zsq[row] - 2.f * p) + esq[col];
      const u64_t kk = ((u64_t)f32_key(dsc) << 32) | (unsigned)col;
      atomicMin(&keys[row], kk);
    }
  }
}

__global__ __launch_bounds__(256) void max_esq(const float* __restrict__ esq,
                                               float* __restrict__ outv) {
  __shared__ float red[256];
  float m = 0.f;
  for (int i = threadIdx.x; i < KE; i += 256) m = fmaxf(m, esq[i]);
  red[threadIdx.x] = m;
  __syncthreads();
  for (int off = 128; off > 0; off >>= 1) {
    if (threadIdx.x < off) red[threadIdx.x] = fmaxf(red[threadIdx.x], red[threadIdx.x + off]);
    __syncthreads();
  }
  if (threadIdx.x == 0) outv[0] = red[0];
}

// thresh key = key( bf16_rowmin + margin ), margin >= 2x bf16 score error bound
__global__ __launch_bounds__(256) void mk_thresh(const unsigned* __restrict__ rowmin,
                                                 const float* __restrict__ zsq,
                                                 const float* __restrict__ maxesq,
                                                 unsigned* __restrict__ thresh) {
  const int r = blockIdx.x * 256 + threadIdx.x;
  const unsigned k = rowmin[r];
  const unsigned u = (k & 0x80000000u) ? (k ^ 0x80000000u) : ~k;
  const float mn = __uint_as_float(u);
  // err(s_bf) <= 2*|dp| <= 2*(2^-7 ||z|| ||e||max); margin = 2^-4*sqrt(zs)*||e||max + 1e-6
  const float marg = sqrtf(zsq[r]) * (0.0625f * sqrtf(maxesq[0])) + 1e-6f;
  thresh[r] = f32_key(mn + marg);
}

// sum of squares per row (256 cols); block = 4 rows x 64 lanes
__global__ __launch_bounds__(256) void rowsq(const float* __restrict__ src,
                                             float* __restrict__ dst, int rows) {
  const int sub = threadIdx.x >> 6;
  const int lane = threadIdx.x & 63;
  const int r = blockIdx.x * 4 + sub;
  if (r >= rows) return;
  const float* p = src + (size_t)r * 256;
  float s = 0.f;
#pragma unroll
  for (int j = 0; j < 4; ++j) {
    float v = p[lane + 64 * j];
    s += v * v;
  }
#pragma unroll
  for (int off = 32; off > 0; off >>= 1) s += __shfl_down(s, off, 64);
  if (lane == 0) dst[r] = s;
}

__global__ __launch_bounds__(256) void init_keys(u64_t* __restrict__ keys) {
  keys[(size_t)blockIdx.x * 256 + threadIdx.x] = ~0ull;
}

__global__ __launch_bounds__(256) void init_rowmin(unsigned* __restrict__ p) {
  p[(size_t)blockIdx.x * 256 + threadIdx.x] = 0xFFFFFFFFu;
}

// per row: idx from key, write z_latent = z + (e - z), quant-loss partial sums
__global__ __launch_bounds__(256) void gather_quant(
    const u64_t* __restrict__ keys, const float* __restrict__ emb,
    const float* __restrict__ z_e, float* __restrict__ zlat,
    int* __restrict__ idx_out, float* __restrict__ qparts) {
  const int sub = threadIdx.x >> 6;
  const int lane = threadIdx.x & 63;
  const int r = blockIdx.x * 4 + sub;
  const int idx = (int)(keys[r] & 0xFFFFFFFFull);
  if (lane == 0) idx_out[r] = idx;
  float s = 0.f;
#pragma unroll
  for (int j = 0; j < 4; ++j) {
    const int d = lane + 64 * j;
    float e = emb[(size_t)idx * 256 + d];
    float z = z_e[(size_t)r * 256 + d];
    float df = e - z;
    s += df * df;
    zlat[(size_t)r * 256 + d] = z + df;  // fl(z_e + fl(z_q - z_e)) — exact ref order
  }
#pragma unroll
  for (int off = 32; off > 0; off >>= 1) s += __shfl_down(s, off, 64);
  __shared__ float red[4];
  if (lane == 0) red[sub] = s;
  __syncthreads();
  if (threadIdx.x == 0) qparts[blockIdx.x] = (red[0] + red[1]) + (red[2] + red[3]);
}

__global__ __launch_bounds__(256) void final_loss(
    const float* __restrict__ qparts, int nq,
    const float* __restrict__ rparts, int nr, float* __restrict__ out) {
  const int tid = threadIdx.x;
  double sq = 0.0, sr = 0.0;
  for (int i = tid; i < nq; i += 256) sq += (double)qparts[i];
  for (int i = tid; i < nr; i += 256) sr += (double)rparts[i];
  __shared__ double bq[256], br[256];
  bq[tid] = sq;
  br[tid] = sr;
  __syncthreads();
  for (int off = 128; off > 0; off >>= 1) {
    if (tid < off) {
      bq[tid] += bq[tid + off];
      br[tid] += br[tid + off];
    }
    __syncthreads();
  }
  if (tid == 0) {
    double qm = bq[0] / ((double)NROWS * 256.0);
    double rm = br[0] / ((double)NROWS * 512.0);
    out[(size_t)NROWS * 256] = (float)(rm + 1.25 * qm);  // recon + (1+BETA)*quant
  }
}

extern "C" void kernel_launch(void* const* d_in, const int* in_sizes, int n_in,
                              void* d_out, int out_size, void* d_ws, size_t ws_size,
                              hipStream_t stream) {
  const float* x   = (const float*)d_in[0];
  const float* ew1 = (const float*)d_in[1];
  const float* eb1 = (const float*)d_in[2];
  const float* ew2 = (const float*)d_in[3];
  const float* eb2 = (const float*)d_in[4];
  const float* ew3 = (const float*)d_in[5];
  const float* eb3 = (const float*)d_in[6];
  const float* dw1 = (const float*)d_in[7];
  const float* db1 = (const float*)d_in[8];
  const float* dw2 = (const float*)d_in[9];
  const float* db2 = (const float*)d_in[10];
  const float* dw3 = (const float*)d_in[11];
  const float* db3 = (const float*)d_in[12];
  const float* emb = (const float*)d_in[13];

  char* ws = (char*)d_ws;
  // region A (offset 0, 33.5 MB): enc h1  ->  e16/rowmin/thresh/maxesq  ->  dec h2
  float* h1        = (float*)(ws);
  unsigned short* e16 = (unsigned short*)(ws);              // 1,048,576 B
  unsigned* rowmin = (unsigned*)(ws + 1048576ull);          // 524,288 B
  unsigned* thresh = (unsigned*)(ws + 1572864ull);          // 524,288 B
  float* maxesq    = (float*)(ws + 2097152ull);             // 256 B
  // region B (offset 33,554,432, 67 MB): enc h2  ->  z16  ->  dec h1
  float* h2        = (float*)(ws + 33554432ull);
  unsigned short* z16 = (unsigned short*)(ws + 33554432ull);  // 67,108,864 B
  // persistent
  float* z_e    = (float*)(ws + 100663296ull);   // N x 256
  float* zsq    = (float*)(ws + 234881024ull);   // N
  float* esq    = (float*)(ws + 235405312ull);   // KE
  u64_t* keys   = (u64_t*)(ws + 235413504ull);   // N
  int* idx      = (int*)(ws + 236462080ull);     // N
  float* qparts = (float*)(ws + 236986368ull);   // N/4
  float* rparts = (float*)(ws + 237117440ull);   // 4096

  float* out = (float*)d_out;
  dim3 blk(256);

  // encoder: 512 -> 64 -> 128 -> 256  (unchanged -> bit-exact z_e)
  gemm64<0><<<dim3(NROWS / 64, 1), blk, 0, stream>>>(x, ew1, eb1, h1, NROWS, 64, 512,
      nullptr);
  gemm128<0><<<dim3(NROWS / 128, 1), blk, 0, stream>>>(h1, ew2, eb2, h2,
      128, 64, nullptr, nullptr, nullptr);
  gemm128<0><<<dim3(NROWS / 128, 2), blk, 0, stream>>>(h2, ew3, eb3, z_e,
      256, 128, nullptr, nullptr, nullptr);

  rowsq<<<dim3(NROWS / 4), blk, 0, stream>>>(z_e, zsq, NROWS);
  rowsq<<<dim3(KE / 4), blk, 0, stream>>>(emb, esq, KE);
  max_esq<<<dim3(1), blk, 0, stream>>>(esq, maxesq);
  init_keys<<<dim3(NROWS / 256), blk, 0, stream>>>(keys);
  init_rowmin<<<dim3(NROWS / 256), blk, 0, stream>>>(rowmin);

  // bf16 copies (h1/h2 regions are dead after enc3)
  cvt_bf16<<<dim3(NROWS * 256 / 8 / 256), blk, 0, stream>>>(z_e, z16, NROWS * 256 / 8);
  cvt_bf16<<<dim3(KE * 256 / 8 / 256), blk, 0, stream>>>(emb, e16, KE * 256 / 8);

  // pass A: per-row bf16 score min
  dist_mfma<0><<<dim3(16384), blk, 0, stream>>>(z16, e16, z_e, emb, zsq, esq,
      rowmin, nullptr, keys);
  mk_thresh<<<dim3(NROWS / 256), blk, 0, stream>>>(rowmin, zsq, maxesq, thresh);
  // pass B: qualify + exact rescore -> keys (bit-identical selection)
  dist_mfma<1><<<dim3(16384), blk, 0, stream>>>(z16, e16, z_e, emb, zsq, esq,
      rowmin, thresh, keys);

  gather_quant<<<dim3(NROWS / 4), blk, 0, stream>>>(keys, emb, z_e, out, idx, qparts);

  // decoder: 256 -> 128 -> 64 -> 512 (loss-only path; z16/e16 dead by now)
  gemm128<1><<<dim3(NROWS / 128, 1), blk, 0, stream>>>(emb, dw1, db1, h2,
      128, 256, idx, nullptr, nullptr);
  gemm64<0><<<dim3(NROWS / 64, 1), blk, 0, stream>>>(h2, dw2, db2, h1, NROWS, 64, 128,
      nullptr);
  gemm128<2><<<dim3(NROWS / 128, 4), blk, 0, stream>>>(h1, dw3, db3, nullptr,
      512, 64, nullptr, x, rparts);

  final_loss<<<dim3(1), blk, 0, stream>>>(qparts, NROWS / 4, rparts, 4096, out);
}

// Round 10
// 1971.681 us; speedup vs baseline: 9.1876x; 1.4833x over previous
//
#include <hip/hip_runtime.h>

#define NROWS 131072
#define KE 2048

typedef unsigned long long u64_t;
typedef __attribute__((ext_vector_type(8))) short bf16x8;
typedef __attribute__((ext_vector_type(4))) float f32x4;

__device__ __forceinline__ unsigned f32_key(float f) {
  unsigned u = __float_as_uint(f);
  return (u & 0x80000000u) ? ~u : (u | 0x80000000u);
}

// ---------------------------------------------------------------------------
// 64x64 tile f32 GEMM (UNCHANGED — enc1/dec2). MODE 0 only.
// ---------------------------------------------------------------------------
template <int MODE>
__global__ __launch_bounds__(256) void gemm64(
    const float* __restrict__ A, const float* __restrict__ B,
    const float* __restrict__ bias, float* __restrict__ C,
    int M, int N, int K,
    const int* __restrict__ gidx) {
  __shared__ __align__(16) float As[16][68];
  __shared__ __align__(16) float Bs[16][68];

  const int tid = threadIdx.x;
  const int tx = tid & 15;
  const int ty = tid >> 4;
  const int arow = blockIdx.x * 64;
  const int bcol = blockIdx.y * 64;

  const int lr = tid >> 2;
  const int lc = (tid & 3) * 4;
  int ga = arow + lr;
  if (MODE == 1) ga = gidx[ga];
  const float* Ap = A + (size_t)ga * K + lc;

  const int bkr = tid >> 4;
  const int bc4 = (tid & 15) * 4;
  const float* Bp = B + (size_t)bkr * N + bcol + bc4;

  float acc[4][4] = {};

  for (int kt = 0; kt < K; kt += 16) {
    float4 av = *reinterpret_cast<const float4*>(Ap);
    As[lc + 0][lr] = av.x;
    As[lc + 1][lr] = av.y;
    As[lc + 2][lr] = av.z;
    As[lc + 3][lr] = av.w;
    float4 bv = *reinterpret_cast<const float4*>(Bp);
    *reinterpret_cast<float4*>(&Bs[bkr][bc4]) = bv;
    Bp += (size_t)16 * N;
    Ap += 16;
    __syncthreads();
#pragma unroll
    for (int k = 0; k < 16; ++k) {
      float4 a = *reinterpret_cast<const float4*>(&As[k][ty * 4]);
      float4 b = *reinterpret_cast<const float4*>(&Bs[k][tx * 4]);
      acc[0][0] += a.x * b.x; acc[0][1] += a.x * b.y; acc[0][2] += a.x * b.z; acc[0][3] += a.x * b.w;
      acc[1][0] += a.y * b.x; acc[1][1] += a.y * b.y; acc[1][2] += a.y * b.z; acc[1][3] += a.y * b.w;
      acc[2][0] += a.z * b.x; acc[2][1] += a.z * b.y; acc[2][2] += a.z * b.z; acc[2][3] += a.z * b.w;
      acc[3][0] += a.w * b.x; acc[3][1] += a.w * b.y; acc[3][2] += a.w * b.z; acc[3][3] += a.w * b.w;
    }
    __syncthreads();
  }

#pragma unroll
  for (int i = 0; i < 4; ++i) {
    const int row = arow + ty * 4 + i;
    float4 v;
    v.x = fmaxf(acc[i][0] + bias[bcol + tx * 4 + 0], 0.f);
    v.y = fmaxf(acc[i][1] + bias[bcol + tx * 4 + 1], 0.f);
    v.z = fmaxf(acc[i][2] + bias[bcol + tx * 4 + 2], 0.f);
    v.w = fmaxf(acc[i][3] + bias[bcol + tx * 4 + 3], 0.f);
    *reinterpret_cast<float4*>(&C[(size_t)row * N + bcol + tx * 4]) = v;
  }
}

// ---------------------------------------------------------------------------
// 128x128 tile f32 GEMM (UNCHANGED — enc2/enc3/dec1/dec3). Modes 0/1/2.
// ---------------------------------------------------------------------------
template <int MODE>
__global__ __launch_bounds__(256) void gemm128(
    const float* __restrict__ A, const float* __restrict__ B,
    const float* __restrict__ bias, float* __restrict__ C,
    int N, int K,
    const int* __restrict__ gidx,
    const float* __restrict__ X,
    float* __restrict__ parts) {
  __shared__ __align__(16) char smem[17408];
  float (*As)[132] = (float(*)[132])smem;
  float (*Bs)[132] = (float(*)[132])(smem + 8448);

  const int tid = threadIdx.x;
  const int tx = tid & 15;
  const int ty = tid >> 4;
  const int arow = blockIdx.x * 128;
  const int bcol = blockIdx.y * 128;

  const int r0 = tid >> 2;
  const int r1 = r0 + 64;
  const int lc = (tid & 3) * 4;
  int ga0 = arow + r0, ga1 = arow + r1;
  if (MODE == 1) { ga0 = gidx[ga0]; ga1 = gidx[ga1]; }
  const float* Ap0 = A + (size_t)ga0 * K + lc;
  const float* Ap1 = A + (size_t)ga1 * K + lc;

  const int bk0 = tid >> 5;
  const int bc0 = (tid & 31) * 4;
  const float* Bp0 = B + (size_t)bk0 * N + bcol + bc0;
  const float* Bp1 = B + (size_t)(bk0 + 8) * N + bcol + bc0;

  float acc[8][8] = {};

  for (int kt = 0; kt < K; kt += 16) {
    float4 a0 = *reinterpret_cast<const float4*>(Ap0);
    float4 a1 = *reinterpret_cast<const float4*>(Ap1);
    As[lc + 0][r0] = a0.x; As[lc + 1][r0] = a0.y; As[lc + 2][r0] = a0.z; As[lc + 3][r0] = a0.w;
    As[lc + 0][r1] = a1.x; As[lc + 1][r1] = a1.y; As[lc + 2][r1] = a1.z; As[lc + 3][r1] = a1.w;
    float4 b0 = *reinterpret_cast<const float4*>(Bp0);
    float4 b1 = *reinterpret_cast<const float4*>(Bp1);
    *reinterpret_cast<float4*>(&Bs[bk0][bc0]) = b0;
    *reinterpret_cast<float4*>(&Bs[bk0 + 8][bc0]) = b1;
    Bp0 += (size_t)16 * N; Bp1 += (size_t)16 * N;
    Ap0 += 16; Ap1 += 16;
    __syncthreads();
#pragma unroll
    for (int k = 0; k < 16; ++k) {
      float4 av0 = *reinterpret_cast<const float4*>(&As[k][ty * 4]);
      float4 av1 = *reinterpret_cast<const float4*>(&As[k][64 + ty * 4]);
      float4 bv0 = *reinterpret_cast<const float4*>(&Bs[k][tx * 4]);
      float4 bv1 = *reinterpret_cast<const float4*>(&Bs[k][64 + tx * 4]);
      const float a[8] = {av0.x, av0.y, av0.z, av0.w, av1.x, av1.y, av1.z, av1.w};
      const float b[8] = {bv0.x, bv0.y, bv0.z, bv0.w, bv1.x, bv1.y, bv1.z, bv1.w};
#pragma unroll
      for (int i = 0; i < 8; ++i)
#pragma unroll
        for (int j = 0; j < 8; ++j) acc[i][j] += a[i] * b[j];
    }
    __syncthreads();
  }

  if (MODE == 0 || MODE == 1) {
#pragma unroll
    for (int i = 0; i < 8; ++i) {
      const int row = arow + (i >> 2) * 64 + ty * 4 + (i & 3);
      const int c0 = bcol + tx * 4;
      const int c1 = bcol + 64 + tx * 4;
      float4 v0, v1;
      v0.x = fmaxf(acc[i][0] + bias[c0 + 0], 0.f);
      v0.y = fmaxf(acc[i][1] + bias[c0 + 1], 0.f);
      v0.z = fmaxf(acc[i][2] + bias[c0 + 2], 0.f);
      v0.w = fmaxf(acc[i][3] + bias[c0 + 3], 0.f);
      v1.x = fmaxf(acc[i][4] + bias[c1 + 0], 0.f);
      v1.y = fmaxf(acc[i][5] + bias[c1 + 1], 0.f);
      v1.z = fmaxf(acc[i][6] + bias[c1 + 2], 0.f);
      v1.w = fmaxf(acc[i][7] + bias[c1 + 3], 0.f);
      *reinterpret_cast<float4*>(&C[(size_t)row * N + c0]) = v0;
      *reinterpret_cast<float4*>(&C[(size_t)row * N + c1]) = v1;
    }
  } else if (MODE == 2) {
    float local = 0.f;
#pragma unroll
    for (int i = 0; i < 8; ++i) {
      const int row = arow + (i >> 2) * 64 + ty * 4 + (i & 3);
#pragma unroll
      for (int j = 0; j < 8; ++j) {
        const int col = bcol + (j >> 2) * 64 + tx * 4 + (j & 3);
        float v = fmaxf(acc[i][j] + bias[col], 0.f);
        float d = v - X[(size_t)row * N + col];
        local += d * d;
      }
    }
    float* rbuf = (float*)smem;
    rbuf[tid] = local;
    __syncthreads();
    for (int off = 128; off > 0; off >>= 1) {
      if (tid < off) rbuf[tid] += rbuf[tid + off];
      __syncthreads();
    }
    if (tid == 0) parts[blockIdx.y * gridDim.x + blockIdx.x] = rbuf[0];
  }
}

// f32 -> bf16 (RNE), 8 elems/thread
__global__ __launch_bounds__(256) void cvt_bf16(const float* __restrict__ src,
                                                unsigned short* __restrict__ dst, int n8) {
  const int i = blockIdx.x * 256 + threadIdx.x;
  if (i >= n8) return;
  const float4 v0 = *reinterpret_cast<const float4*>(src + (size_t)i * 8);
  const float4 v1 = *reinterpret_cast<const float4*>(src + (size_t)i * 8 + 4);
  const float f[8] = {v0.x, v0.y, v0.z, v0.w, v1.x, v1.y, v1.z, v1.w};
  unsigned short s[8];
#pragma unroll
  for (int j = 0; j < 8; ++j) {
    unsigned u = __float_as_uint(f[j]);
    u += 0x7FFFu + ((u >> 16) & 1u);
    s[j] = (unsigned short)(u >> 16);
  }
  uint4 o;
  o.x = (unsigned)s[0] | ((unsigned)s[1] << 16);
  o.y = (unsigned)s[2] | ((unsigned)s[3] << 16);
  o.z = (unsigned)s[4] | ((unsigned)s[5] << 16);
  o.w = (unsigned)s[6] | ((unsigned)s[7] << 16);
  *reinterpret_cast<uint4*>(dst + (size_t)i * 8) = o;
}

// ---------------------------------------------------------------------------
// dist_fused: one block = 128 rows x ALL 2048 cols. A-frags (z16) resident in
// registers (16 bf16x8/lane, loaded once); e16 streamed via double-buffered
// LDS, k-chunk-major layout [4][128 rows][8 shorts] (reads & writes 2-way
// bank aliasing = free, all 16B aligned). One barrier per (ct,kb) tile,
// global loads issued at iteration top (r6 schedule).
// Sweep 0: bf16 scores -> per-lane min -> shfl reduce -> per-row threshold
//          (margin >= 2x bf16 error bound, validated bit-exact in r9).
// Sweep 1: identical MFMA recompute -> qualify vs threshold -> exact f32
//          rescore (ascending-k fma chain + (zs-2p)+esq, rounds-1..8 exact)
//          -> u64 atomicMin keys. Selection bit-identical to reference.
// ---------------------------------------------------------------------------
__global__ __launch_bounds__(256, 1) void dist_fused(
    const unsigned short* __restrict__ z16, const unsigned short* __restrict__ e16,
    const float* __restrict__ zf, const float* __restrict__ ef,
    const float* __restrict__ zsq, const float* __restrict__ esq,
    const float* __restrict__ maxesq, u64_t* __restrict__ keys) {
  __shared__ __align__(16) short Bs[2][4096];  // 2 x 8192 B
  __shared__ unsigned thr_s[128];

  const int tid = threadIdx.x;
  const int l15 = tid & 15;
  const int lk = (tid >> 4) & 3;
  const int w = tid >> 6;
  const int arow = blockIdx.x * 128;

  // A fragments, resident: rows (arow + w*32 + fr*16 + l15), k = kb*32 + lk*8
  bf16x8 a[2][8];
  {
    const unsigned short* za = z16 + (size_t)(arow + w * 32 + l15) * 256 + lk * 8;
#pragma unroll
    for (int fr = 0; fr < 2; ++fr)
#pragma unroll
      for (int kb = 0; kb < 8; ++kb)
        a[fr][kb] = *reinterpret_cast<const bf16x8*>(za + fr * 16 * 256 + kb * 32);
  }

  // B staging mapping: thread -> rows (tid>>2, +64), k-chunk (tid&3)
  const int srow = tid >> 2;
  const int sch = tid & 3;
  uint4 sa0, sa1;

  unsigned minkey[2][4];
#pragma unroll
  for (int fr = 0; fr < 2; ++fr)
#pragma unroll
    for (int rg = 0; rg < 4; ++rg) minkey[fr][rg] = 0xFFFFFFFFu;
  unsigned thrv[2][4];

  int qv[16];
  int qn = 0;

  // exact rescore of one candidate (rounds-1..8 arithmetic, bit-identical)
  auto rescore = [&](int e) {
    const int row = arow + (e >> 11);
    const int col = e & 2047;
    const float* zp = zf + (size_t)row * 256;
    const float* ep = ef + (size_t)col * 256;
    float p = 0.f;
    for (int k4 = 0; k4 < 256; k4 += 4) {
      const float4 zv = *reinterpret_cast<const float4*>(zp + k4);
      const float4 ev = *reinterpret_cast<const float4*>(ep + k4);
      p = fmaf(zv.x, ev.x, p);
      p = fmaf(zv.y, ev.y, p);
      p = fmaf(zv.z, ev.z, p);
      p = fmaf(zv.w, ev.w, p);
    }
    const float dsc = (zsq[row] - 2.f * p) + esq[col];
    const u64_t kk = ((u64_t)f32_key(dsc) << 32) | (unsigned)col;
    atomicMin(&keys[row], kk);
  };

  for (int sweep = 0; sweep < 2; ++sweep) {
    // pipeline prologue: tile 0 -> buffer 0
    {
      const unsigned short* p = e16 + (size_t)srow * 256 + sch * 8;
      sa0 = *reinterpret_cast<const uint4*>(p);
      sa1 = *reinterpret_cast<const uint4*>(p + 64 * 256);
    }
    __syncthreads();  // prior-sweep Bs reads / thr_s reads complete
    *reinterpret_cast<uint4*>(&Bs[0][sch * 1024 + srow * 8]) = sa0;
    *reinterpret_cast<uint4*>(&Bs[0][sch * 1024 + (srow + 64) * 8]) = sa1;

    for (int ct = 0; ct < 16; ++ct) {
      f32x4 acc[2][8];
#pragma unroll
      for (int fr = 0; fr < 2; ++fr)
#pragma unroll
        for (int fc = 0; fc < 8; ++fc) acc[fr][fc] = (f32x4){0.f, 0.f, 0.f, 0.f};

#pragma unroll 1
      for (int kb = 0; kb < 8; ++kb) {
        const int ti = ct * 8 + kb;
        if (ti < 127) {  // issue next-tile global loads early
          const int tn = ti + 1;
          const unsigned short* p =
              e16 + (size_t)((tn >> 3) * 128 + srow) * 256 + (tn & 7) * 32 + sch * 8;
          sa0 = *reinterpret_cast<const uint4*>(p);
          sa1 = *reinterpret_cast<const uint4*>(p + 64 * 256);
        }
        __syncthreads();  // buf[ti&1] writes visible; buf[ti&1^1] reads done
        const int buf = ti & 1;
        bf16x8 b[8];
#pragma unroll
        for (int fc = 0; fc < 8; ++fc)
          b[fc] = *reinterpret_cast<const bf16x8*>(&Bs[buf][lk * 1024 + (fc * 16 + l15) * 8]);
#pragma unroll
        for (int fc = 0; fc < 8; ++fc) {
          acc[0][fc] = __builtin_amdgcn_mfma_f32_16x16x32_bf16(a[0][kb], b[fc], acc[0][fc], 0, 0, 0);
          acc[1][fc] = __builtin_amdgcn_mfma_f32_16x16x32_bf16(a[1][kb], b[fc], acc[1][fc], 0, 0, 0);
        }
        if (ti < 127) {
          *reinterpret_cast<uint4*>(&Bs[buf ^ 1][sch * 1024 + srow * 8]) = sa0;
          *reinterpret_cast<uint4*>(&Bs[buf ^ 1][sch * 1024 + (srow + 64) * 8]) = sa1;
        }
      }

      // per-ct epilogue: scores s = esq - 2*p_bf  (zsq dropped: row-constant)
      float esqv[8];
#pragma unroll
      for (int fc = 0; fc < 8; ++fc) esqv[fc] = esq[ct * 128 + fc * 16 + l15];

      if (sweep == 0) {
#pragma unroll
        for (int fr = 0; fr < 2; ++fr)
#pragma unroll
          for (int rg = 0; rg < 4; ++rg) {
            unsigned k = minkey[fr][rg];
#pragma unroll
            for (int fc = 0; fc < 8; ++fc) {
              const unsigned kk = f32_key(fmaf(-2.f, acc[fr][fc][rg], esqv[fc]));
              if (kk < k) k = kk;
            }
            minkey[fr][rg] = k;
          }
      } else {
#pragma unroll
        for (int fr = 0; fr < 2; ++fr)
#pragma unroll
          for (int rg = 0; rg < 4; ++rg) {
            const unsigned tk = thrv[fr][rg];
            const int rowoff = w * 32 + fr * 16 + lk * 4 + rg;
#pragma unroll
            for (int fc = 0; fc < 8; ++fc) {
              const unsigned kk = f32_key(fmaf(-2.f, acc[fr][fc][rg], esqv[fc]));
              if (kk <= tk) {
                if (qn == 16) {  // overflow-safe flush
                  for (int c = 0; c < 16; ++c) rescore(qv[c]);
                  qn = 0;
                }
                qv[qn++] = (rowoff << 11) | (ct * 128 + fc * 16 + l15);
              }
            }
          }
      }
    }

    if (sweep == 0) {
      // cross-lane row-min (lanes differing in l15 bits), then thresholds
#pragma unroll
      for (int fr = 0; fr < 2; ++fr)
#pragma unroll
        for (int rg = 0; rg < 4; ++rg) {
          unsigned k = minkey[fr][rg];
#pragma unroll
          for (int m = 1; m < 16; m <<= 1) {
            const unsigned o = (unsigned)__shfl_xor((int)k, m, 64);
            if (o < k) k = o;
          }
          if (l15 == 0) {
            const int rowib = w * 32 + fr * 16 + lk * 4 + rg;
            const unsigned u = (k & 0x80000000u) ? (k ^ 0x80000000u) : ~k;
            const float mn = __uint_as_float(u);
            // margin >= 2x bf16 score-error bound (r9-validated)
            const float marg = sqrtf(zsq[arow + rowib]) * (0.0625f * sqrtf(maxesq[0])) + 1e-6f;
            thr_s[rowib] = f32_key(mn + marg);
          }
        }
      __syncthreads();
#pragma unroll
      for (int fr = 0; fr < 2; ++fr)
#pragma unroll
        for (int rg = 0; rg < 4; ++rg)
          thrv[fr][rg] = thr_s[w * 32 + fr * 16 + lk * 4 + rg];
    }
  }

  for (int c = 0; c < qn; ++c) rescore(qv[c]);
}

__global__ __launch_bounds__(256) void max_esq(const float* __restrict__ esq,
                                               float* __restrict__ outv) {
  __shared__ float red[256];
  float m = 0.f;
  for (int i = threadIdx.x; i < KE; i += 256) m = fmaxf(m, esq[i]);
  red[threadIdx.x] = m;
  __syncthreads();
  for (int off = 128; off > 0; off >>= 1) {
    if (threadIdx.x < off) red[threadIdx.x] = fmaxf(red[threadIdx.x], red[threadIdx.x + off]);
    __syncthreads();
  }
  if (threadIdx.x == 0) outv[0] = red[0];
}

// sum of squares per row (256 cols); block = 4 rows x 64 lanes
__global__ __launch_bounds__(256) void rowsq(const float* __restrict__ src,
                                             float* __restrict__ dst, int rows) {
  const int sub = threadIdx.x >> 6;
  const int lane = threadIdx.x & 63;
  const int r = blockIdx.x * 4 + sub;
  if (r >= rows) return;
  const float* p = src + (size_t)r * 256;
  float s = 0.f;
#pragma unroll
  for (int j = 0; j < 4; ++j) {
    float v = p[lane + 64 * j];
    s += v * v;
  }
#pragma unroll
  for (int off = 32; off > 0; off >>= 1) s += __shfl_down(s, off, 64);
  if (lane == 0) dst[r] = s;
}

__global__ __launch_bounds__(256) void init_keys(u64_t* __restrict__ keys) {
  keys[(size_t)blockIdx.x * 256 + threadIdx.x] = ~0ull;
}

// per row: idx from key, write z_latent = z + (e - z), quant-loss partial sums
__global__ __launch_bounds__(256) void gather_quant(
    const u64_t* __restrict__ keys, const float* __restrict__ emb,
    const float* __restrict__ z_e, float* __restrict__ zlat,
    int* __restrict__ idx_out, float* __restrict__ qparts) {
  const int sub = threadIdx.x >> 6;
  const int lane = threadIdx.x & 63;
  const int r = blockIdx.x * 4 + sub;
  const int idx = (int)(keys[r] & 0xFFFFFFFFull);
  if (lane == 0) idx_out[r] = idx;
  float s = 0.f;
#pragma unroll
  for (int j = 0; j < 4; ++j) {
    const int d = lane + 64 * j;
    float e = emb[(size_t)idx * 256 + d];
    float z = z_e[(size_t)r * 256 + d];
    float df = e - z;
    s += df * df;
    zlat[(size_t)r * 256 + d] = z + df;  // fl(z_e + fl(z_q - z_e)) — exact ref order
  }
#pragma unroll
  for (int off = 32; off > 0; off >>= 1) s += __shfl_down(s, off, 64);
  __shared__ float red[4];
  if (lane == 0) red[sub] = s;
  __syncthreads();
  if (threadIdx.x == 0) qparts[blockIdx.x] = (red[0] + red[1]) + (red[2] + red[3]);
}

__global__ __launch_bounds__(256) void final_loss(
    const float* __restrict__ qparts, int nq,
    const float* __restrict__ rparts, int nr, float* __restrict__ out) {
  const int tid = threadIdx.x;
  double sq = 0.0, sr = 0.0;
  for (int i = tid; i < nq; i += 256) sq += (double)qparts[i];
  for (int i = tid; i < nr; i += 256) sr += (double)rparts[i];
  __shared__ double bq[256], br[256];
  bq[tid] = sq;
  br[tid] = sr;
  __syncthreads();
  for (int off = 128; off > 0; off >>= 1) {
    if (tid < off) {
      bq[tid] += bq[tid + off];
      br[tid] += br[tid + off];
    }
    __syncthreads();
  }
  if (tid == 0) {
    double qm = bq[0] / ((double)NROWS * 256.0);
    double rm = br[0] / ((double)NROWS * 512.0);
    out[(size_t)NROWS * 256] = (float)(rm + 1.25 * qm);  // recon + (1+BETA)*quant
  }
}

extern "C" void kernel_launch(void* const* d_in, const int* in_sizes, int n_in,
                              void* d_out, int out_size, void* d_ws, size_t ws_size,
                              hipStream_t stream) {
  const float* x   = (const float*)d_in[0];
  const float* ew1 = (const float*)d_in[1];
  const float* eb1 = (const float*)d_in[2];
  const float* ew2 = (const float*)d_in[3];
  const float* eb2 = (const float*)d_in[4];
  const float* ew3 = (const float*)d_in[5];
  const float* eb3 = (const float*)d_in[6];
  const float* dw1 = (const float*)d_in[7];
  const float* db1 = (const float*)d_in[8];
  const float* dw2 = (const float*)d_in[9];
  const float* db2 = (const float*)d_in[10];
  const float* dw3 = (const float*)d_in[11];
  const float* db3 = (const float*)d_in[12];
  const float* emb = (const float*)d_in[13];

  char* ws = (char*)d_ws;
  // region A (offset 0, 33.5 MB): enc h1 -> e16/maxesq -> dec h2
  float* h1           = (float*)(ws);
  unsigned short* e16 = (unsigned short*)(ws);              // 1,048,576 B
  float* maxesq       = (float*)(ws + 2097152ull);          // 256 B
  // region B (offset 33,554,432, 67 MB): enc h2 -> z16 -> dec h1
  float* h2           = (float*)(ws + 33554432ull);
  unsigned short* z16 = (unsigned short*)(ws + 33554432ull);  // 67,108,864 B
  // persistent
  float* z_e    = (float*)(ws + 100663296ull);   // N x 256
  float* zsq    = (float*)(ws + 234881024ull);   // N
  float* esq    = (float*)(ws + 235405312ull);   // KE
  u64_t* keys   = (u64_t*)(ws + 235413504ull);   // N
  int* idx      = (int*)(ws + 236462080ull);     // N
  float* qparts = (float*)(ws + 236986368ull);   // N/4
  float* rparts = (float*)(ws + 237117440ull);   // 4096

  float* out = (float*)d_out;
  dim3 blk(256);

  // encoder: 512 -> 64 -> 128 -> 256  (unchanged -> bit-exact z_e)
  gemm64<0><<<dim3(NROWS / 64, 1), blk, 0, stream>>>(x, ew1, eb1, h1, NROWS, 64, 512,
      nullptr);
  gemm128<0><<<dim3(NROWS / 128, 1), blk, 0, stream>>>(h1, ew2, eb2, h2,
      128, 64, nullptr, nullptr, nullptr);
  gemm128<0><<<dim3(NROWS / 128, 2), blk, 0, stream>>>(h2, ew3, eb3, z_e,
      256, 128, nullptr, nullptr, nullptr);

  rowsq<<<dim3(NROWS / 4), blk, 0, stream>>>(z_e, zsq, NROWS);
  rowsq<<<dim3(KE / 4), blk, 0, stream>>>(emb, esq, KE);
  max_esq<<<dim3(1), blk, 0, stream>>>(esq, maxesq);
  init_keys<<<dim3(NROWS / 256), blk, 0, stream>>>(keys);

  // bf16 copies (h1/h2 regions are dead after enc3)
  cvt_bf16<<<dim3(NROWS * 256 / 8 / 256), blk, 0, stream>>>(z_e, z16, NROWS * 256 / 8);
  cvt_bf16<<<dim3(KE * 256 / 8 / 256), blk, 0, stream>>>(emb, e16, KE * 256 / 8);

  // fused bound + exact-rescore argmin (bit-identical selection)
  dist_fused<<<dim3(NROWS / 128), blk, 0, stream>>>(z16, e16, z_e, emb, zsq, esq,
      maxesq, keys);

  gather_quant<<<dim3(NROWS / 4), blk, 0, stream>>>(keys, emb, z_e, out, idx, qparts);

  // decoder: 256 -> 128 -> 64 -> 512 (loss-only path; z16/e16 dead by now)
  gemm128<1><<<dim3(NROWS / 128, 1), blk, 0, stream>>>(emb, dw1, db1, h2,
      128, 256, idx, nullptr, nullptr);
  gemm64<0><<<dim3(NROWS / 64, 1), blk, 0, stream>>>(h2, dw2, db2, h1, NROWS, 64, 128,
      nullptr);
  gemm128<2><<<dim3(NROWS / 128, 4), blk, 0, stream>>>(h1, dw3, db3, nullptr,
      512, 64, nullptr, x, rparts);

  final_loss<<<dim3(1), blk, 0, stream>>>(qparts, NROWS / 4, rparts, 4096, out);
}